// Round 14
// baseline (80055.634 us; speedup 1.0000x reference)
//
#include <hip/hip_runtime.h>
#include <math.h>

#define Bb 64
#define Ll 1024
#define Dd 512
#define G4 2048        // 4*D
#define KK 16          // factor-block length
#define PART_STRIDE 532  // 512 acc + m + ssum + 16 gamma + pad
#define WSL 12         // writer K-slices (12 x 128 = 1536)
#define RSL 8          // reader K-slices (8 x 128 = 1024)

__device__ __forceinline__ float hsig(float v){ return fminf(fmaxf(0.2f*v + 0.5f, 0.f), 1.f); }

// ---------------- one-time: Wf = [Wc@Ww ; Uw]  (1536 x 2048), bf = bc@Ww + bw ----------------
__global__ __launch_bounds__(256) void wf_build(const float* __restrict__ Wc, const float* __restrict__ Ww,
                                                const float* __restrict__ Uw, float* __restrict__ Wf){
    const int k0 = (blockIdx.x >> 3) * 16;
    const int j  = (blockIdx.x & 7) * 256 + threadIdx.x;
    if (k0 < 2 * Dd){
        float acc[16];
        #pragma unroll
        for (int kk = 0; kk < 16; ++kk) acc[kk] = 0.f;
        for (int m = 0; m < Dd; ++m){
            float wv = Ww[(size_t)m * G4 + j];
            #pragma unroll
            for (int kk = 0; kk < 16; ++kk)
                acc[kk] = fmaf(Wc[(size_t)(k0 + kk) * Dd + m], wv, acc[kk]);
        }
        #pragma unroll
        for (int kk = 0; kk < 16; ++kk) Wf[(size_t)(k0 + kk) * G4 + j] = acc[kk];
    } else {
        #pragma unroll
        for (int kk = 0; kk < 16; ++kk)
            Wf[(size_t)(k0 + kk) * G4 + j] = Uw[(size_t)(k0 + kk - 2 * Dd) * G4 + j];
    }
}

__global__ __launch_bounds__(256) void bf_build(const float* __restrict__ bc, const float* __restrict__ Ww,
                                                const float* __restrict__ bw, float* __restrict__ bf){
    int j = blockIdx.x * 256 + threadIdx.x;
    float s = bw[j];
    for (int m = 0; m < Dd; ++m) s = fmaf(bc[m], Ww[(size_t)m * G4 + j], s);
    bf[j] = s;
}

// ---------------- reader gate GEMM (prologue t=0 only; 4-slice layout matched with reader_pw) ----------------
__global__ __launch_bounds__(256) void gemm_reader(const float* __restrict__ xt, const float* __restrict__ h,
                                                   const float* __restrict__ Wr, const float* __restrict__ Ur,
                                                   float* __restrict__ part){
    __shared__ float inT[64][65];
    __shared__ float wT[64][32];
    const int bx = blockIdx.x;
    const int jt = bx & 63, ks = bx >> 6;
    const int j0 = jt * 32;
    const int k0 = ks * 256;
    const int tid = threadIdx.x;
    const int tj4 = (tid & 7) * 4;
    const int tb  = tid >> 3;
    float a00=0.f,a01=0.f,a02=0.f,a03=0.f;
    float a10=0.f,a11=0.f,a12=0.f,a13=0.f;
    for (int kk = 0; kk < 256; kk += 64){
        #pragma unroll
        for (int i = 0; i < 16; ++i){
            int idx = tid + i * 256;
            int b = idx >> 6, k = idx & 63;
            int kg = k0 + kk + k;
            inT[b][k] = (kg < Dd) ? xt[(size_t)b * (Ll * Dd) + kg] : h[b * Dd + kg - Dd];
        }
        #pragma unroll
        for (int i = 0; i < 8; ++i){
            int idx = tid + i * 256;
            int k = idx >> 5, j = idx & 31;
            int kg = k0 + kk + k;
            wT[k][j] = (kg < Dd) ? Wr[(size_t)kg * G4 + j0 + j] : Ur[(size_t)(kg - Dd) * G4 + j0 + j];
        }
        __syncthreads();
        #pragma unroll 8
        for (int k = 0; k < 64; ++k){
            float4 wv = *(const float4*)&wT[k][tj4];
            float i0 = inT[tb][k];
            float i1 = inT[tb + 32][k];
            a00 = fmaf(i0, wv.x, a00); a01 = fmaf(i0, wv.y, a01);
            a02 = fmaf(i0, wv.z, a02); a03 = fmaf(i0, wv.w, a03);
            a10 = fmaf(i1, wv.x, a10); a11 = fmaf(i1, wv.y, a11);
            a12 = fmaf(i1, wv.z, a12); a13 = fmaf(i1, wv.w, a13);
        }
        __syncthreads();
    }
    size_t o0 = (size_t)(ks * Bb + tb) * G4 + j0 + tj4;
    size_t o1 = (size_t)(ks * Bb + tb + 32) * G4 + j0 + tj4;
    *(float4*)&part[o0] = make_float4(a00, a01, a02, a03);
    *(float4*)&part[o1] = make_float4(a10, a11, a12, a13);
}

__global__ __launch_bounds__(256) void reader_pw(const float* __restrict__ part, const float* __restrict__ br,
                                                 float* __restrict__ h, float* __restrict__ c){
    int idx = blockIdx.x * 256 + threadIdx.x;
    int b = idx >> 9, d = idx & 511;
    float z[4];
    #pragma unroll
    for (int g = 0; g < 4; ++g){
        int j = g * Dd + d;
        float s = br[j];
        #pragma unroll
        for (int ks = 0; ks < 4; ++ks) s += part[(size_t)(ks * Bb + b) * G4 + j];
        z[g] = s;
    }
    float i = hsig(z[0]), f = hsig(z[1]), g2 = tanhf(z[2]), o = hsig(z[3]);
    float cn = fmaf(f, c[idx], i * g2);
    c[idx] = cn;
    h[idx] = o * tanhf(cn);
}

// ---------------- gemm_fast: double-buffered, float4-staged step GEMM (R13, verified) ----------------
__global__ __launch_bounds__(256) void gemm_fast(const float* __restrict__ o, const float* __restrict__ mrt,
                                                 const float* __restrict__ hw, const float* __restrict__ Wf,
                                                 float* __restrict__ partW,
                                                 const float* __restrict__ xt1, const float* __restrict__ Wr,
                                                 const float* __restrict__ Ur, float* __restrict__ partR){
    __shared__ float inT[2][64][68];
    __shared__ float wT[2][64][36];
    const int bxg = blockIdx.x;
    const bool writer = (bxg < WSL * 64);
    const int bx = writer ? bxg : bxg - WSL * 64;
    const int jt = bx & 63;
    const int ks = bx >> 6;
    const int j0 = jt * 32;
    const int k0 = ks * 128;
    const int tid = threadIdx.x;
    const int tj4 = (tid & 7) * 4;
    const int tb  = tid >> 3;

    float4 aR0, aR1, aR2, aR3, wR0, wR1;
    auto LOAD = [&](int kk){
        #pragma unroll
        for (int i = 0; i < 4; ++i){
            int lin = tid + i * 256;
            int b = lin >> 4, k4 = (lin & 15) * 4;
            int kg = k0 + kk + k4;
            const float* src;
            if (writer){
                if (kg < Dd)           src = o   + b * Dd + kg;
                else if (kg < 2 * Dd)  src = mrt + b * Dd + kg - Dd;
                else                   src = hw  + b * Dd + kg - 2 * Dd;
            } else {
                src = (kg < Dd) ? xt1 + (size_t)b * (Ll * Dd) + kg
                                : o + b * Dd + kg - Dd;
            }
            float4 v = *(const float4*)src;
            if (i == 0) aR0 = v; else if (i == 1) aR1 = v; else if (i == 2) aR2 = v; else aR3 = v;
        }
        #pragma unroll
        for (int i = 0; i < 2; ++i){
            int lin = tid + i * 256;
            int k = lin >> 3, j4 = (lin & 7) * 4;
            int kg = k0 + kk + k;
            const float* src;
            if (writer) src = Wf + (size_t)kg * G4 + j0 + j4;
            else        src = (kg < Dd) ? Wr + (size_t)kg * G4 + j0 + j4
                                        : Ur + (size_t)(kg - Dd) * G4 + j0 + j4;
            float4 v = *(const float4*)src;
            if (i == 0) wR0 = v; else wR1 = v;
        }
    };
    auto STORE = [&](int buf){
        #pragma unroll
        for (int i = 0; i < 4; ++i){
            int lin = tid + i * 256;
            int b = lin >> 4, k4 = (lin & 15) * 4;
            float4 v = (i == 0) ? aR0 : (i == 1) ? aR1 : (i == 2) ? aR2 : aR3;
            *(float4*)&inT[buf][b][k4] = v;
        }
        #pragma unroll
        for (int i = 0; i < 2; ++i){
            int lin = tid + i * 256;
            int k = lin >> 3, j4 = (lin & 7) * 4;
            float4 v = (i == 0) ? wR0 : wR1;
            *(float4*)&wT[buf][k][j4] = v;
        }
    };

    float a00=0.f,a01=0.f,a02=0.f,a03=0.f;
    float a10=0.f,a11=0.f,a12=0.f,a13=0.f;

    LOAD(0);
    STORE(0);
    __syncthreads();
    LOAD(64);
    #pragma unroll 8
    for (int k = 0; k < 64; ++k){
        float4 wv = *(const float4*)&wT[0][k][tj4];
        float i0 = inT[0][tb][k];
        float i1 = inT[0][tb + 32][k];
        a00 = fmaf(i0, wv.x, a00); a01 = fmaf(i0, wv.y, a01);
        a02 = fmaf(i0, wv.z, a02); a03 = fmaf(i0, wv.w, a03);
        a10 = fmaf(i1, wv.x, a10); a11 = fmaf(i1, wv.y, a11);
        a12 = fmaf(i1, wv.z, a12); a13 = fmaf(i1, wv.w, a13);
    }
    STORE(1);
    __syncthreads();
    #pragma unroll 8
    for (int k = 0; k < 64; ++k){
        float4 wv = *(const float4*)&wT[1][k][tj4];
        float i0 = inT[1][tb][k];
        float i1 = inT[1][tb + 32][k];
        a00 = fmaf(i0, wv.x, a00); a01 = fmaf(i0, wv.y, a01);
        a02 = fmaf(i0, wv.z, a02); a03 = fmaf(i0, wv.w, a03);
        a10 = fmaf(i1, wv.x, a10); a11 = fmaf(i1, wv.y, a11);
        a12 = fmaf(i1, wv.z, a12); a13 = fmaf(i1, wv.w, a13);
    }
    float* part = writer ? partW : partR;
    size_t o0 = (size_t)(ks * Bb + tb) * G4 + j0 + tj4;
    size_t o1 = (size_t)(ks * Bb + tb + 32) * G4 + j0 + tj4;
    *(float4*)&part[o0] = make_float4(a00, a01, a02, a03);
    *(float4*)&part[o1] = make_float4(a10, a11, a12, a13);
}

// ---------------- FUSED PW: blocks [0,128) = writer_pw(t) [12 slices], [128,256) = reader_pw(t+1) [8] ----------------
__global__ __launch_bounds__(256) void pw_both(const float* __restrict__ partW, const float* __restrict__ bfv,
                                               float* __restrict__ hw, float* __restrict__ cw,
                                               float* __restrict__ out, int last,
                                               const float* __restrict__ partR, const float* __restrict__ br,
                                               float* __restrict__ h, float* __restrict__ c){
    const int bxg = blockIdx.x;
    const int writer = (bxg < 128) ? 1 : 0;
    const int idx = (writer ? bxg : bxg - 128) * 256 + threadIdx.x;
    const int b = idx >> 9, d = idx & 511;
    float z[4];
    #pragma unroll
    for (int g = 0; g < 4; ++g){
        int j = g * Dd + d;
        float s;
        if (writer){
            s = bfv[j];
            #pragma unroll
            for (int sl = 0; sl < WSL; ++sl) s += partW[(size_t)(sl * Bb + b) * G4 + j];
        } else {
            s = br[j];
            #pragma unroll
            for (int sl = 0; sl < RSL; ++sl) s += partR[(size_t)(sl * Bb + b) * G4 + j];
        }
        z[g] = s;
    }
    float i = hsig(z[0]), f = hsig(z[1]), g2 = tanhf(z[2]), o = hsig(z[3]);
    if (writer){
        float cn = fmaf(f, cw[idx], i * g2);
        cw[idx] = cn;
        float hn = o * tanhf(cn);
        hw[idx] = hn;
        if (last) out[idx] = hn;
    } else {
        float cn = fmaf(f, c[idx], i * g2);
        c[idx] = cn;
        h[idx] = o * tanhf(cn);
    }
}

// ---------------- MEGA_FACTOR: read-only factored pass (modes 0 and 2; no HWL, no mem store) ----------------
__global__ __launch_bounds__(256, 4) void mega_factor(const float* __restrict__ memB,
                                                      const float* __restrict__ o,
                                                      float* __restrict__ scores, const float* __restrict__ Mb,
                                                      const float* __restrict__ Sinv,
                                                      float* __restrict__ part,
                                                      float* __restrict__ Dv, float* __restrict__ Cv,
                                                      const float* __restrict__ hwring,
                                                      int mode, int p){
    __shared__ float DL[64];
    __shared__ float CORRL[64];
    __shared__ float CL[64][KK];
    __shared__ float GL[KK];
    const int bid = blockIdx.x;
    const int b = bid >> 4, lb = bid & 15;
    const int tid = threadIdx.x;
    const int lane = tid & 63;
    const int wvi = tid >> 6;
    const int gw = lb * 4 + wvi;
    const int d0 = lane * 4, d1 = 256 + lane * 4;

    if (mode == 2){
        for (int ii = wvi; ii < p; ii += 4){
            const float* ov = o + b * Dd + lane * 8;
            const float* hv = hwring + ((size_t)ii * Bb + b) * Dd + lane * 8;
            float4 x0 = *(const float4*)ov;
            float4 x1 = *(const float4*)(ov + 4);
            float4 y0 = *(const float4*)hv;
            float4 y1 = *(const float4*)(hv + 4);
            float s = x0.x*y0.x + x0.y*y0.y + x0.z*y0.z + x0.w*y0.w
                    + x1.x*y1.x + x1.y*y1.y + x1.z*y1.z + x1.w*y1.w;
            #pragma unroll
            for (int off = 32; off; off >>= 1) s += __shfl_xor(s, off);
            if (lane == 0) GL[ii] = s;
        }
        __syncthreads();

        if (tid < 64){
            const int l = lb * 64 + tid;
            const size_t cbase = (size_t)(b * Ll + l) * KK;
            float z = __expf(scores[b * Ll + l] - Mb[b]) * Sinv[b];
            float om = 1.f - z;
            const int pm1 = p - 1;
            float cl[KK];
            float Dn;
            if (pm1 == 0){
                Dn = om;
                #pragma unroll
                for (int i = 0; i < KK; ++i) cl[i] = 0.f;
            } else {
                Dn = Dv[b * Ll + l] * om;
                #pragma unroll
                for (int i = 0; i < KK; ++i) cl[i] = Cv[cbase + i] * om;
                #pragma unroll
                for (int i = 0; i < KK; ++i) if (i > pm1) cl[i] = 0.f;
            }
            cl[pm1] = z;
            DL[tid] = Dn;
            #pragma unroll
            for (int i = 0; i < KK; ++i) CL[tid][i] = cl[i];
            Dv[b * Ll + l] = Dn;
            #pragma unroll
            for (int i = 0; i < KK; ++i) Cv[cbase + i] = cl[i];
            float corr = 0.f;
            #pragma unroll
            for (int i = 0; i < KK; ++i) corr = fmaf(cl[i], (i < p) ? GL[i] : 0.f, corr);
            CORRL[tid] = corr;
        }
        __syncthreads();
    }

    float4 oa  = *(const float4*)(o + b * Dd + d0);
    float4 obv = *(const float4*)(o + b * Dd + d1);
    const int lbase = gw * 16;
    float* srow = scores + b * Ll;

    float mA = -INFINITY, sAs = 0.f, mB = -INFINITY, sBs = 0.f;
    float A0x=0.f,A0y=0.f,A0z=0.f,A0w=0.f, A1x=0.f,A1y=0.f,A1z=0.f,A1w=0.f;
    float B0x=0.f,B0y=0.f,B0z=0.f,B0w=0.f, B1x=0.f,B1y=0.f,B1z=0.f,B1w=0.f;
    float my_s = 0.f;
    size_t baseA = ((size_t)b * Ll + lbase) * Dd;
    size_t baseB = baseA + (size_t)8 * Dd;

    #pragma unroll 2
    for (int r = 0; r < 8; ++r){
        const int locA = wvi * 16 + r, locB = locA + 8;
        float4 vA0 = *(const float4*)(memB + baseA + d0);
        float4 vA1 = *(const float4*)(memB + baseA + d1);
        float4 vB0 = *(const float4*)(memB + baseB + d0);
        float4 vB1 = *(const float4*)(memB + baseB + d1);
        float sa = vA0.x*oa.x + vA0.y*oa.y + vA0.z*oa.z + vA0.w*oa.w
                 + vA1.x*obv.x + vA1.y*obv.y + vA1.z*obv.z + vA1.w*obv.w;
        float sb = vB0.x*oa.x + vB0.y*oa.y + vB0.z*oa.z + vB0.w*oa.w
                 + vB1.x*obv.x + vB1.y*obv.y + vB1.z*obv.z + vB1.w*obv.w;
        #pragma unroll
        for (int off = 32; off; off >>= 1){
            sa += __shfl_xor(sa, off);
            sb += __shfl_xor(sb, off);
        }
        float DnA = 1.f, DnB = 1.f;
        if (mode == 2){
            DnA = DL[locA]; DnB = DL[locB];
            sa = fmaf(DnA, sa, CORRL[locA]);
            sb = fmaf(DnB, sb, CORRL[locB]);
        }
        if (lane == 0){ srow[lbase + r] = sa; srow[lbase + 8 + r] = sb; }
        if (lane == r)     my_s = sa;
        if (lane == 8 + r) my_s = sb;
        float nmA = fmaxf(mA, sa);
        float scA = __expf(mA - nmA);
        float wtA = __expf(sa - nmA);
        float wdA = wtA * DnA;
        sAs = fmaf(sAs, scA, wtA);
        A0x = fmaf(A0x, scA, vA0.x * wdA); A0y = fmaf(A0y, scA, vA0.y * wdA);
        A0z = fmaf(A0z, scA, vA0.z * wdA); A0w = fmaf(A0w, scA, vA0.w * wdA);
        A1x = fmaf(A1x, scA, vA1.x * wdA); A1y = fmaf(A1y, scA, vA1.y * wdA);
        A1z = fmaf(A1z, scA, vA1.z * wdA); A1w = fmaf(A1w, scA, vA1.w * wdA);
        mA = nmA;
        float nmB = fmaxf(mB, sb);
        float scB = __expf(mB - nmB);
        float wtB = __expf(sb - nmB);
        float wdB = wtB * DnB;
        sBs = fmaf(sBs, scB, wtB);
        B0x = fmaf(B0x, scB, vB0.x * wdB); B0y = fmaf(B0y, scB, vB0.y * wdB);
        B0z = fmaf(B0z, scB, vB0.z * wdB); B0w = fmaf(B0w, scB, vB0.w * wdB);
        B1x = fmaf(B1x, scB, vB1.x * wdB); B1y = fmaf(B1y, scB, vB1.y * wdB);
        B1z = fmaf(B1z, scB, vB1.z * wdB); B1w = fmaf(B1w, scB, vB1.w * wdB);
        mB = nmB;
        baseA += Dd; baseB += Dd;
    }
    float M = fmaxf(mA, mB);
    float eA = __expf(mA - M), eB = __expf(mB - M);
    float ssum = sAs * eA + sBs * eB;
    float* pp = part + (size_t)(b * 64 + gw) * PART_STRIDE;
    *(float4*)(pp + d0) = make_float4(A0x * eA + B0x * eB, A0y * eA + B0y * eB,
                                      A0z * eA + B0z * eB, A0w * eA + B0w * eB);
    *(float4*)(pp + d1) = make_float4(A1x * eA + B1x * eB, A1y * eA + B1y * eB,
                                      A1z * eA + B1z * eB, A1w * eA + B1w * eB);
    if (lane == 0){ pp[512] = M; pp[513] = ssum; }
    if (mode == 2){
        // gamma_i = sum over this wave's 16 rows of exp(s_r - M) * c_{r,i}
        float wexp = (lane < 16) ? __expf(my_s - M) : 0.f;
        float gacc = 0.f;
        const int ci = lane & 15;
        #pragma unroll
        for (int l = 0; l < 16; ++l){
            float wl = __shfl(wexp, l);
            gacc = fmaf(wl, CL[wvi * 16 + l][ci], gacc);
        }
        if (lane < 16) pp[514 + lane] = gacc;
    }
}

// ---------------- MEGA_MAT: materialize mem = D*memB + sum c_i hw_i, direct scores/read ----------------
__global__ __launch_bounds__(256, 4) void mega_mat(const float* __restrict__ memB, float* __restrict__ memOut,
                                                   const float* __restrict__ o,
                                                   float* __restrict__ scores, const float* __restrict__ Mb,
                                                   const float* __restrict__ Sinv,
                                                   float* __restrict__ part,
                                                   const float* __restrict__ Dv, const float* __restrict__ Cv,
                                                   const float* __restrict__ hwring){
    __shared__ float DL[64];
    __shared__ float CL[64][KK];
    __shared__ float HWL[KK][Dd];
    const int bid = blockIdx.x;
    const int b = bid >> 4, lb = bid & 15;
    const int tid = threadIdx.x;
    const int lane = tid & 63;
    const int wvi = tid >> 6;
    const int gw = lb * 4 + wvi;
    const int d0 = lane * 4, d1 = 256 + lane * 4;

    if (tid < 64){
        const int l = lb * 64 + tid;
        const size_t cbase = (size_t)(b * Ll + l) * KK;
        float z = __expf(scores[b * Ll + l] - Mb[b]) * Sinv[b];
        float om = 1.f - z;
        float cl[KK];
        float Dn = Dv[b * Ll + l] * om;
        #pragma unroll
        for (int i = 0; i < KK; ++i) cl[i] = Cv[cbase + i] * om;
        cl[KK - 1] = z;
        DL[tid] = Dn;
        #pragma unroll
        for (int i = 0; i < KK; ++i) CL[tid][i] = cl[i];
    }
    for (int i = tid; i < KK * Dd; i += 256){
        int s = i >> 9, d = i & 511;
        HWL[s][d] = hwring[((size_t)s * Bb + b) * Dd + d];
    }
    __syncthreads();

    float4 oa  = *(const float4*)(o + b * Dd + d0);
    float4 obv = *(const float4*)(o + b * Dd + d1);
    const int lbase = gw * 16;
    float* srow = scores + b * Ll;

    float mA = -INFINITY, sAs = 0.f, mB = -INFINITY, sBs = 0.f;
    float A0x=0.f,A0y=0.f,A0z=0.f,A0w=0.f, A1x=0.f,A1y=0.f,A1z=0.f,A1w=0.f;
    float B0x=0.f,B0y=0.f,B0z=0.f,B0w=0.f, B1x=0.f,B1y=0.f,B1z=0.f,B1w=0.f;
    size_t baseA = ((size_t)b * Ll + lbase) * Dd;
    size_t baseB = baseA + (size_t)8 * Dd;

    #pragma unroll 2
    for (int r = 0; r < 8; ++r){
        const int locA = wvi * 16 + r, locB = locA + 8;
        float4 vA0 = *(const float4*)(memB + baseA + d0);
        float4 vA1 = *(const float4*)(memB + baseA + d1);
        float4 vB0 = *(const float4*)(memB + baseB + d0);
        float4 vB1 = *(const float4*)(memB + baseB + d1);
        float DnA = DL[locA], DnB = DL[locB];
        vA0.x *= DnA; vA0.y *= DnA; vA0.z *= DnA; vA0.w *= DnA;
        vA1.x *= DnA; vA1.y *= DnA; vA1.z *= DnA; vA1.w *= DnA;
        vB0.x *= DnB; vB0.y *= DnB; vB0.z *= DnB; vB0.w *= DnB;
        vB1.x *= DnB; vB1.y *= DnB; vB1.z *= DnB; vB1.w *= DnB;
        #pragma unroll
        for (int i = 0; i < KK; ++i){
            float cA = CL[locA][i], cB = CL[locB][i];
            float4 h0 = *(const float4*)&HWL[i][d0];
            float4 h1 = *(const float4*)&HWL[i][d1];
            vA0.x = fmaf(cA, h0.x, vA0.x); vA0.y = fmaf(cA, h0.y, vA0.y);
            vA0.z = fmaf(cA, h0.z, vA0.z); vA0.w = fmaf(cA, h0.w, vA0.w);
            vA1.x = fmaf(cA, h1.x, vA1.x); vA1.y = fmaf(cA, h1.y, vA1.y);
            vA1.z = fmaf(cA, h1.z, vA1.z); vA1.w = fmaf(cA, h1.w, vA1.w);
            vB0.x = fmaf(cB, h0.x, vB0.x); vB0.y = fmaf(cB, h0.y, vB0.y);
            vB0.z = fmaf(cB, h0.z, vB0.z); vB0.w = fmaf(cB, h0.w, vB0.w);
            vB1.x = fmaf(cB, h1.x, vB1.x); vB1.y = fmaf(cB, h1.y, vB1.y);
            vB1.z = fmaf(cB, h1.z, vB1.z); vB1.w = fmaf(cB, h1.w, vB1.w);
        }
        *(float4*)(memOut + baseA + d0) = vA0;
        *(float4*)(memOut + baseA + d1) = vA1;
        *(float4*)(memOut + baseB + d0) = vB0;
        *(float4*)(memOut + baseB + d1) = vB1;
        float sa = vA0.x*oa.x + vA0.y*oa.y + vA0.z*oa.z + vA0.w*oa.w
                 + vA1.x*obv.x + vA1.y*obv.y + vA1.z*obv.z + vA1.w*obv.w;
        float sb = vB0.x*oa.x + vB0.y*oa.y + vB0.z*oa.z + vB0.w*oa.w
                 + vB1.x*obv.x + vB1.y*obv.y + vB1.z*obv.z + vB1.w*obv.w;
        #pragma unroll
        for (int off = 32; off; off >>= 1){
            sa += __shfl_xor(sa, off);
            sb += __shfl_xor(sb, off);
        }
        if (lane == 0){ srow[lbase + r] = sa; srow[lbase + 8 + r] = sb; }
        float nmA = fmaxf(mA, sa);
        float scA = __expf(mA - nmA);
        float wtA = __expf(sa - nmA);
        sAs = fmaf(sAs, scA, wtA);
        A0x = fmaf(A0x, scA, vA0.x * wtA); A0y = fmaf(A0y, scA, vA0.y * wtA);
        A0z = fmaf(A0z, scA, vA0.z * wtA); A0w = fmaf(A0w, scA, vA0.w * wtA);
        A1x = fmaf(A1x, scA, vA1.x * wtA); A1y = fmaf(A1y, scA, vA1.y * wtA);
        A1z = fmaf(A1z, scA, vA1.z * wtA); A1w = fmaf(A1w, scA, vA1.w * wtA);
        mA = nmA;
        float nmB = fmaxf(mB, sb);
        float scB = __expf(mB - nmB);
        float wtB = __expf(sb - nmB);
        sBs = fmaf(sBs, scB, wtB);
        B0x = fmaf(B0x, scB, vB0.x * wtB); B0y = fmaf(B0y, scB, vB0.y * wtB);
        B0z = fmaf(B0z, scB, vB0.z * wtB); B0w = fmaf(B0w, scB, vB0.w * wtB);
        B1x = fmaf(B1x, scB, vB1.x * wtB); B1y = fmaf(B1y, scB, vB1.y * wtB);
        B1z = fmaf(B1z, scB, vB1.z * wtB); B1w = fmaf(B1w, scB, vB1.w * wtB);
        mB = nmB;
        baseA += Dd; baseB += Dd;
    }
    float M = fmaxf(mA, mB);
    float eA = __expf(mA - M), eB = __expf(mB - M);
    float ssum = sAs * eA + sBs * eB;
    float* pp = part + (size_t)(b * 64 + gw) * PART_STRIDE;
    *(float4*)(pp + d0) = make_float4(A0x * eA + B0x * eB, A0y * eA + B0y * eB,
                                      A0z * eA + B0z * eB, A0w * eA + B0w * eB);
    *(float4*)(pp + d1) = make_float4(A1x * eA + B1x * eB, A1y * eA + B1y * eB,
                                      A1z * eA + B1z * eB, A1w * eA + B1w * eB);
    if (lane == 0){ pp[512] = M; pp[513] = ssum; }
}

// ---------------- finalize: 64 wave partials -> m_rt (+ factored hw correction), M, 1/S ----------------
__global__ __launch_bounds__(256) void small_a(const float* __restrict__ part, float* __restrict__ mrt,
                                               float* __restrict__ Mb, float* __restrict__ Sinv,
                                               const float* __restrict__ hwring, int p){
    const int b = blockIdx.x >> 2, dseg = blockIdx.x & 3;
    const int tid = threadIdx.x;
    __shared__ float ews[64];
    __shared__ float psum[256];
    __shared__ float gam[KK][8];
    if (tid < 64){
        const float* pp = part + (size_t)(b * 64 + tid) * PART_STRIDE;
        float mw = pp[512], sw = pp[513];
        float M = mw;
        #pragma unroll
        for (int off = 32; off; off >>= 1) M = fmaxf(M, __shfl_xor(M, off));
        float e = __expf(mw - M);
        float Ssum = sw * e;
        #pragma unroll
        for (int off = 32; off; off >>= 1) Ssum += __shfl_xor(Ssum, off);
        float Si = 1.f / Ssum;
        ews[tid] = e * Si;
        if (dseg == 0 && tid == 0){ Mb[b] = M; Sinv[b] = Si; }
    }
    __syncthreads();
    if (p > 0 && tid < 128){
        const int i = tid & 15, ch = tid >> 4;   // ch 0..7, 8 waves-partials each
        float s = 0.f;
        #pragma unroll
        for (int w2 = 0; w2 < 8; ++w2)
            s = fmaf(part[(size_t)(b * 64 + ch * 8 + w2) * PART_STRIDE + 514 + i], ews[ch * 8 + w2], s);
        gam[i][ch] = s;
    }
    __syncthreads();
    if (p > 0 && tid < 16){
        float s = gam[tid][0];
        #pragma unroll
        for (int ch = 1; ch < 8; ++ch) s += gam[tid][ch];
        gam[tid][0] = s;
    }
    const int dl = tid & 127, half = tid >> 7;
    const int d = dseg * 128 + dl;
    const float* pb = part + (size_t)(b * 64 + half * 32) * PART_STRIDE + d;
    float s = 0.f;
    #pragma unroll 8
    for (int w2 = 0; w2 < 32; ++w2)
        s = fmaf(pb[(size_t)w2 * PART_STRIDE], ews[half * 32 + w2], s);
    psum[tid] = s;
    __syncthreads();
    if (half == 0){
        float r = psum[tid] + psum[tid + 128];
        for (int i = 0; i < p; ++i)
            r = fmaf(gam[i][0], hwring[((size_t)i * Bb + b) * Dd + d], r);
        mrt[b * Dd + d] = r;
    }
}

extern "C" void kernel_launch(void* const* d_in, const int* in_sizes, int n_in,
                              void* d_out, int out_size, void* d_ws, size_t ws_size,
                              hipStream_t stream) {
    (void)in_sizes; (void)n_in; (void)out_size;
    const float* x  = (const float*)d_in[0];
    const float* Wr = (const float*)d_in[1];
    const float* Ur = (const float*)d_in[2];
    const float* br = (const float*)d_in[3];
    const float* Ww = (const float*)d_in[4];
    const float* Uw = (const float*)d_in[5];
    const float* bw = (const float*)d_in[6];
    const float* Wc = (const float*)d_in[7];
    const float* bc = (const float*)d_in[8];
    float* out = (float*)d_out;

    float* w = (float*)d_ws;
    float* mem     = w; w += (size_t)Bb * Ll * Dd;
    float* scores  = w; w += (size_t)Bb * Ll;
    float* part_me = w; w += (size_t)Bb * 64 * PART_STRIDE;
    float* Mb      = w; w += 64;
    float* Sinv    = w; w += 64;
    float* mrt     = w; w += (size_t)Bb * Dd;
    float* Dv      = w; w += (size_t)Bb * Ll;
    float* Cv      = w; w += (size_t)Bb * Ll * KK;
    float* h_r     = w; w += (size_t)Bb * Dd;     // memset region: h_r,c_r,cw,hwring
    float* c_r     = w; w += (size_t)Bb * Dd;
    float* cw      = w; w += (size_t)Bb * Dd;
    float* hwring  = w; w += (size_t)KK * Bb * Dd;
    float* partR   = w; w += (size_t)RSL * Bb * G4;
    float* partW   = w; w += (size_t)WSL * Bb * G4;
    float* Wf      = w; w += (size_t)1536 * G4;
    float* bf      = w; w += G4;
    size_t need = (size_t)(w - (float*)d_ws) * sizeof(float);
    if (ws_size < need) return;

    hipMemsetAsync(h_r, 0, (size_t)(3 + KK) * Bb * Dd * sizeof(float), stream);
    wf_build<<<(1536 / 16) * 8, 256, 0, stream>>>(Wc, Ww, Uw, Wf);
    bf_build<<<G4 / 256, 256, 0, stream>>>(bc, Ww, bw, bf);

    // prologue: reader step 0
    gemm_reader<<<256, 256, 0, stream>>>(x, h_r, Wr, Ur, partR);
    reader_pw<<<128, 256, 0, stream>>>(partR, br, h_r, c_r);

    for (int t = 0; t < Ll; ++t){
        const int p = t & (KK - 1);
        const int mode = (t == 0) ? 0 : ((p == 0) ? 1 : 2);
        const float* mi = (t <= KK) ? x : mem;   // memB = x until first materialize (t==KK) writes mem
        if (mode == 1)
            mega_mat<<<1024, 256, 0, stream>>>(mi, mem, h_r, scores, Mb, Sinv, part_me,
                                               Dv, Cv, hwring);
        else
            mega_factor<<<1024, 256, 0, stream>>>(mi, h_r, scores, Mb, Sinv, part_me,
                                                  Dv, Cv, hwring, mode, p);
        small_a<<<256, 256, 0, stream>>>(part_me, mrt, Mb, Sinv, hwring, (mode == 2) ? p : 0);
        int tn = (t + 1 < Ll) ? t + 1 : t;
        const float* hwprev = hwring + ((size_t)((t + KK - 1) & (KK - 1)) * Bb) * Dd;
        gemm_fast<<<(WSL + RSL) * 64, 256, 0, stream>>>(h_r, mrt, hwprev, Wf, partW,
                                                        x + (size_t)tn * Dd, Wr, Ur, partR);
        float* hwnew = hwring + ((size_t)(t & (KK - 1)) * Bb) * Dd;
        pw_both<<<256, 256, 0, stream>>>(partW, bf, hwnew, cw, out, t == Ll - 1 ? 1 : 0,
                                         partR, br, h_r, c_r);
    }
}

// Round 15
// 69168.188 us; speedup vs baseline: 1.1574x; 1.1574x over previous
//
#include <hip/hip_runtime.h>
#include <math.h>

#define Bb 64
#define Ll 1024
#define Dd 512
#define G4 2048        // 4*D
#define KK 8           // factor-block length
#define PART_STRIDE 524  // 512 acc + m + ssum + 8 gamma + pad
#define WSL 12         // writer K-slices (12 x 128 = 1536)
#define RSL 8          // reader K-slices (8 x 128 = 1024)

typedef unsigned int uint;
typedef unsigned short ushort;

__device__ __forceinline__ float hsig(float v){ return fminf(fmaxf(0.2f*v + 0.5f, 0.f), 1.f); }
__device__ __forceinline__ float b2f(uint s){ return __uint_as_float(s << 16); }
__device__ __forceinline__ ushort f2b(float f){
    uint u = __float_as_uint(f);
    return (ushort)((u + 0x7fffu + ((u >> 16) & 1u)) >> 16);   // RNE, finite inputs
}

// ---------------- one-time: Wf = [Wc@Ww ; Uw]  (1536 x 2048), bf = bc@Ww + bw ----------------
__global__ __launch_bounds__(256) void wf_build(const float* __restrict__ Wc, const float* __restrict__ Ww,
                                                const float* __restrict__ Uw, float* __restrict__ Wf){
    const int k0 = (blockIdx.x >> 3) * 16;
    const int j  = (blockIdx.x & 7) * 256 + threadIdx.x;
    if (k0 < 2 * Dd){
        float acc[16];
        #pragma unroll
        for (int kk = 0; kk < 16; ++kk) acc[kk] = 0.f;
        for (int m = 0; m < Dd; ++m){
            float wv = Ww[(size_t)m * G4 + j];
            #pragma unroll
            for (int kk = 0; kk < 16; ++kk)
                acc[kk] = fmaf(Wc[(size_t)(k0 + kk) * Dd + m], wv, acc[kk]);
        }
        #pragma unroll
        for (int kk = 0; kk < 16; ++kk) Wf[(size_t)(k0 + kk) * G4 + j] = acc[kk];
    } else {
        #pragma unroll
        for (int kk = 0; kk < 16; ++kk)
            Wf[(size_t)(k0 + kk) * G4 + j] = Uw[(size_t)(k0 + kk - 2 * Dd) * G4 + j];
    }
}

__global__ __launch_bounds__(256) void bf_build(const float* __restrict__ bc, const float* __restrict__ Ww,
                                                const float* __restrict__ bw, float* __restrict__ bf){
    int j = blockIdx.x * 256 + threadIdx.x;
    float s = bw[j];
    for (int m = 0; m < Dd; ++m) s = fmaf(bc[m], Ww[(size_t)m * G4 + j], s);
    bf[j] = s;
}

// ---------------- one-time: x (fp32) -> memB16 (bf16 shadow) ----------------
__global__ __launch_bounds__(256) void conv_b(const float* __restrict__ x, ushort* __restrict__ mB){
    size_t i = ((size_t)blockIdx.x * 256 + threadIdx.x) * 8;
    float4 a = *(const float4*)(x + i);
    float4 c = *(const float4*)(x + i + 4);
    uint4 st;
    st.x = (uint)f2b(a.x) | ((uint)f2b(a.y) << 16);
    st.y = (uint)f2b(a.z) | ((uint)f2b(a.w) << 16);
    st.z = (uint)f2b(c.x) | ((uint)f2b(c.y) << 16);
    st.w = (uint)f2b(c.z) | ((uint)f2b(c.w) << 16);
    *(uint4*)(mB + i) = st;
}

// ---------------- reader gate GEMM (prologue t=0 only) ----------------
__global__ __launch_bounds__(256) void gemm_reader(const float* __restrict__ xt, const float* __restrict__ h,
                                                   const float* __restrict__ Wr, const float* __restrict__ Ur,
                                                   float* __restrict__ part){
    __shared__ float inT[64][65];
    __shared__ float wT[64][32];
    const int bx = blockIdx.x;
    const int jt = bx & 63, ks = bx >> 6;
    const int j0 = jt * 32;
    const int k0 = ks * 256;
    const int tid = threadIdx.x;
    const int tj4 = (tid & 7) * 4;
    const int tb  = tid >> 3;
    float a00=0.f,a01=0.f,a02=0.f,a03=0.f;
    float a10=0.f,a11=0.f,a12=0.f,a13=0.f;
    for (int kk = 0; kk < 256; kk += 64){
        #pragma unroll
        for (int i = 0; i < 16; ++i){
            int idx = tid + i * 256;
            int b = idx >> 6, k = idx & 63;
            int kg = k0 + kk + k;
            inT[b][k] = (kg < Dd) ? xt[(size_t)b * (Ll * Dd) + kg] : h[b * Dd + kg - Dd];
        }
        #pragma unroll
        for (int i = 0; i < 8; ++i){
            int idx = tid + i * 256;
            int k = idx >> 5, j = idx & 31;
            int kg = k0 + kk + k;
            wT[k][j] = (kg < Dd) ? Wr[(size_t)kg * G4 + j0 + j] : Ur[(size_t)(kg - Dd) * G4 + j0 + j];
        }
        __syncthreads();
        #pragma unroll 8
        for (int k = 0; k < 64; ++k){
            float4 wv = *(const float4*)&wT[k][tj4];
            float i0 = inT[tb][k];
            float i1 = inT[tb + 32][k];
            a00 = fmaf(i0, wv.x, a00); a01 = fmaf(i0, wv.y, a01);
            a02 = fmaf(i0, wv.z, a02); a03 = fmaf(i0, wv.w, a03);
            a10 = fmaf(i1, wv.x, a10); a11 = fmaf(i1, wv.y, a11);
            a12 = fmaf(i1, wv.z, a12); a13 = fmaf(i1, wv.w, a13);
        }
        __syncthreads();
    }
    size_t o0 = (size_t)(ks * Bb + tb) * G4 + j0 + tj4;
    size_t o1 = (size_t)(ks * Bb + tb + 32) * G4 + j0 + tj4;
    *(float4*)&part[o0] = make_float4(a00, a01, a02, a03);
    *(float4*)&part[o1] = make_float4(a10, a11, a12, a13);
}

__global__ __launch_bounds__(256) void reader_pw(const float* __restrict__ part, const float* __restrict__ br,
                                                 float* __restrict__ h, float* __restrict__ c){
    int idx = blockIdx.x * 256 + threadIdx.x;
    int b = idx >> 9, d = idx & 511;
    float z[4];
    #pragma unroll
    for (int g = 0; g < 4; ++g){
        int j = g * Dd + d;
        float s = br[j];
        #pragma unroll
        for (int ks = 0; ks < 4; ++ks) s += part[(size_t)(ks * Bb + b) * G4 + j];
        z[g] = s;
    }
    float i = hsig(z[0]), f = hsig(z[1]), g2 = tanhf(z[2]), o = hsig(z[3]);
    float cn = fmaf(f, c[idx], i * g2);
    c[idx] = cn;
    h[idx] = o * tanhf(cn);
}

// ---------------- gemm_fast: double-buffered, float4-staged step GEMM (R13, verified) ----------------
__global__ __launch_bounds__(256) void gemm_fast(const float* __restrict__ o, const float* __restrict__ mrt,
                                                 const float* __restrict__ hw, const float* __restrict__ Wf,
                                                 float* __restrict__ partW,
                                                 const float* __restrict__ xt1, const float* __restrict__ Wr,
                                                 const float* __restrict__ Ur, float* __restrict__ partR){
    __shared__ float inT[2][64][68];
    __shared__ float wT[2][64][36];
    const int bxg = blockIdx.x;
    const bool writer = (bxg < WSL * 64);
    const int bx = writer ? bxg : bxg - WSL * 64;
    const int jt = bx & 63;
    const int ks = bx >> 6;
    const int j0 = jt * 32;
    const int k0 = ks * 128;
    const int tid = threadIdx.x;
    const int tj4 = (tid & 7) * 4;
    const int tb  = tid >> 3;

    float4 aR0, aR1, aR2, aR3, wR0, wR1;
    auto LOAD = [&](int kk){
        #pragma unroll
        for (int i = 0; i < 4; ++i){
            int lin = tid + i * 256;
            int b = lin >> 4, k4 = (lin & 15) * 4;
            int kg = k0 + kk + k4;
            const float* src;
            if (writer){
                if (kg < Dd)           src = o   + b * Dd + kg;
                else if (kg < 2 * Dd)  src = mrt + b * Dd + kg - Dd;
                else                   src = hw  + b * Dd + kg - 2 * Dd;
            } else {
                src = (kg < Dd) ? xt1 + (size_t)b * (Ll * Dd) + kg
                                : o + b * Dd + kg - Dd;
            }
            float4 v = *(const float4*)src;
            if (i == 0) aR0 = v; else if (i == 1) aR1 = v; else if (i == 2) aR2 = v; else aR3 = v;
        }
        #pragma unroll
        for (int i = 0; i < 2; ++i){
            int lin = tid + i * 256;
            int k = lin >> 3, j4 = (lin & 7) * 4;
            int kg = k0 + kk + k;
            const float* src;
            if (writer) src = Wf + (size_t)kg * G4 + j0 + j4;
            else        src = (kg < Dd) ? Wr + (size_t)kg * G4 + j0 + j4
                                        : Ur + (size_t)(kg - Dd) * G4 + j0 + j4;
            float4 v = *(const float4*)src;
            if (i == 0) wR0 = v; else wR1 = v;
        }
    };
    auto STORE = [&](int buf){
        #pragma unroll
        for (int i = 0; i < 4; ++i){
            int lin = tid + i * 256;
            int b = lin >> 4, k4 = (lin & 15) * 4;
            float4 v = (i == 0) ? aR0 : (i == 1) ? aR1 : (i == 2) ? aR2 : aR3;
            *(float4*)&inT[buf][b][k4] = v;
        }
        #pragma unroll
        for (int i = 0; i < 2; ++i){
            int lin = tid + i * 256;
            int k = lin >> 3, j4 = (lin & 7) * 4;
            float4 v = (i == 0) ? wR0 : wR1;
            *(float4*)&wT[buf][k][j4] = v;
        }
    };

    float a00=0.f,a01=0.f,a02=0.f,a03=0.f;
    float a10=0.f,a11=0.f,a12=0.f,a13=0.f;

    LOAD(0);
    STORE(0);
    __syncthreads();
    LOAD(64);
    #pragma unroll 8
    for (int k = 0; k < 64; ++k){
        float4 wv = *(const float4*)&wT[0][k][tj4];
        float i0 = inT[0][tb][k];
        float i1 = inT[0][tb + 32][k];
        a00 = fmaf(i0, wv.x, a00); a01 = fmaf(i0, wv.y, a01);
        a02 = fmaf(i0, wv.z, a02); a03 = fmaf(i0, wv.w, a03);
        a10 = fmaf(i1, wv.x, a10); a11 = fmaf(i1, wv.y, a11);
        a12 = fmaf(i1, wv.z, a12); a13 = fmaf(i1, wv.w, a13);
    }
    STORE(1);
    __syncthreads();
    #pragma unroll 8
    for (int k = 0; k < 64; ++k){
        float4 wv = *(const float4*)&wT[1][k][tj4];
        float i0 = inT[1][tb][k];
        float i1 = inT[1][tb + 32][k];
        a00 = fmaf(i0, wv.x, a00); a01 = fmaf(i0, wv.y, a01);
        a02 = fmaf(i0, wv.z, a02); a03 = fmaf(i0, wv.w, a03);
        a10 = fmaf(i1, wv.x, a10); a11 = fmaf(i1, wv.y, a11);
        a12 = fmaf(i1, wv.z, a12); a13 = fmaf(i1, wv.w, a13);
    }
    float* part = writer ? partW : partR;
    size_t o0 = (size_t)(ks * Bb + tb) * G4 + j0 + tj4;
    size_t o1 = (size_t)(ks * Bb + tb + 32) * G4 + j0 + tj4;
    *(float4*)&part[o0] = make_float4(a00, a01, a02, a03);
    *(float4*)&part[o1] = make_float4(a10, a11, a12, a13);
}

// ---------------- FUSED PW: blocks [0,128) = writer_pw(t) [12 slices], [128,256) = reader_pw(t+1) [8] ----------------
__global__ __launch_bounds__(256) void pw_both(const float* __restrict__ partW, const float* __restrict__ bfv,
                                               float* __restrict__ hw, float* __restrict__ cw,
                                               float* __restrict__ out, int last,
                                               const float* __restrict__ partR, const float* __restrict__ br,
                                               float* __restrict__ h, float* __restrict__ c){
    const int bxg = blockIdx.x;
    const int writer = (bxg < 128) ? 1 : 0;
    const int idx = (writer ? bxg : bxg - 128) * 256 + threadIdx.x;
    const int b = idx >> 9, d = idx & 511;
    float z[4];
    #pragma unroll
    for (int g = 0; g < 4; ++g){
        int j = g * Dd + d;
        float s;
        if (writer){
            s = bfv[j];
            #pragma unroll
            for (int sl = 0; sl < WSL; ++sl) s += partW[(size_t)(sl * Bb + b) * G4 + j];
        } else {
            s = br[j];
            #pragma unroll
            for (int sl = 0; sl < RSL; ++sl) s += partR[(size_t)(sl * Bb + b) * G4 + j];
        }
        z[g] = s;
    }
    float i = hsig(z[0]), f = hsig(z[1]), g2 = tanhf(z[2]), o = hsig(z[3]);
    if (writer){
        float cn = fmaf(f, cw[idx], i * g2);
        cw[idx] = cn;
        float hn = o * tanhf(cn);
        hw[idx] = hn;
        if (last) out[idx] = hn;
    } else {
        float cn = fmaf(f, c[idx], i * g2);
        c[idx] = cn;
        h[idx] = o * tanhf(cn);
    }
}

// ---------------- MEGA3: factored attention pass; FACTOR reads bf16 shadow, MAT writes fp32 + shadow ----------------
__global__ __launch_bounds__(256, 4) void mega3(const float* memB, float* memOut,
                                                const ushort* __restrict__ mB16, ushort* __restrict__ mB16out,
                                                const float* __restrict__ o,
                                                float* __restrict__ scores, const float* __restrict__ Mb,
                                                const float* __restrict__ Sinv,
                                                float* __restrict__ part,
                                                float* __restrict__ Dv, float* __restrict__ Cv,
                                                const float* __restrict__ hwring,
                                                int mode, int p){
    __shared__ float DL[64];
    __shared__ float CORRL[64];
    __shared__ float CL[64][KK];
    __shared__ float GL[KK];
    __shared__ float HWL[KK][Dd];
    const int bid = blockIdx.x;
    const int b = bid >> 4, lb = bid & 15;
    const int tid = threadIdx.x;
    const int lane = tid & 63;
    const int wvi = tid >> 6;
    const int gw = lb * 4 + wvi;
    const int d0 = lane * 4, d1 = 256 + lane * 4;

    if (mode == 2){
        for (int ii = wvi; ii < p; ii += 4){
            const float* ov = o + b * Dd + lane * 8;
            const float* hv = hwring + ((size_t)ii * Bb + b) * Dd + lane * 8;
            float4 x0 = *(const float4*)ov;
            float4 x1 = *(const float4*)(ov + 4);
            float4 y0 = *(const float4*)hv;
            float4 y1 = *(const float4*)(hv + 4);
            float s = x0.x*y0.x + x0.y*y0.y + x0.z*y0.z + x0.w*y0.w
                    + x1.x*y1.x + x1.y*y1.y + x1.z*y1.z + x1.w*y1.w;
            #pragma unroll
            for (int off = 32; off; off >>= 1) s += __shfl_xor(s, off);
            if (lane == 0) GL[ii] = s;
        }
        __syncthreads();
    }

    if (mode){
        if (tid < 64){
            const int l = lb * 64 + tid;
            const size_t cbase = (size_t)(b * Ll + l) * KK;
            float z = __expf(scores[b * Ll + l] - Mb[b]) * Sinv[b];
            float om = 1.f - z;
            const int pm1 = (mode == 1) ? (KK - 1) : (p - 1);
            float cl[KK];
            float Dn;
            if (pm1 == 0){
                Dn = om;
                #pragma unroll
                for (int i = 0; i < KK; ++i) cl[i] = 0.f;
            } else {
                Dn = Dv[b * Ll + l] * om;
                #pragma unroll
                for (int i = 0; i < KK; ++i) cl[i] = Cv[cbase + i] * om;
                #pragma unroll
                for (int i = 0; i < KK; ++i) if (i > pm1) cl[i] = 0.f;
            }
            cl[pm1] = z;
            DL[tid] = Dn;
            #pragma unroll
            for (int i = 0; i < KK; ++i) CL[tid][i] = cl[i];
            if (mode == 2){
                Dv[b * Ll + l] = Dn;
                #pragma unroll
                for (int i = 0; i < KK; ++i) Cv[cbase + i] = cl[i];
                float corr = 0.f;
                #pragma unroll
                for (int i = 0; i < KK; ++i) corr = fmaf(cl[i], (i < p) ? GL[i] : 0.f, corr);
                CORRL[tid] = corr;
            }
        }
        if (mode == 1){
            for (int i = tid; i < KK * Dd; i += 256){
                int s = i >> 9, d = i & 511;
                HWL[s][d] = hwring[((size_t)s * Bb + b) * Dd + d];
            }
        }
        __syncthreads();
    }

    float4 oa  = *(const float4*)(o + b * Dd + d0);
    float4 obv = *(const float4*)(o + b * Dd + d1);
    const int lbase = gw * 16;
    float* srow = scores + b * Ll;

    float mA = -INFINITY, sAs = 0.f, mB = -INFINITY, sBs = 0.f;
    float A0x=0.f,A0y=0.f,A0z=0.f,A0w=0.f, A1x=0.f,A1y=0.f,A1z=0.f,A1w=0.f;
    float B0x=0.f,B0y=0.f,B0z=0.f,B0w=0.f, B1x=0.f,B1y=0.f,B1z=0.f,B1w=0.f;
    float my_s = 0.f;
    size_t baseA = ((size_t)b * Ll + lbase) * Dd;
    size_t baseB = baseA + (size_t)8 * Dd;

    if (mode == 1){
        #pragma unroll 2
        for (int r = 0; r < 8; ++r){
            const int locA = wvi * 16 + r, locB = locA + 8;
            float4 vA0 = *(const float4*)(memB + baseA + d0);
            float4 vA1 = *(const float4*)(memB + baseA + d1);
            float4 vB0 = *(const float4*)(memB + baseB + d0);
            float4 vB1 = *(const float4*)(memB + baseB + d1);
            float DnA = DL[locA], DnB = DL[locB];
            vA0.x *= DnA; vA0.y *= DnA; vA0.z *= DnA; vA0.w *= DnA;
            vA1.x *= DnA; vA1.y *= DnA; vA1.z *= DnA; vA1.w *= DnA;
            vB0.x *= DnB; vB0.y *= DnB; vB0.z *= DnB; vB0.w *= DnB;
            vB1.x *= DnB; vB1.y *= DnB; vB1.z *= DnB; vB1.w *= DnB;
            #pragma unroll
            for (int i = 0; i < KK; ++i){
                float cA = CL[locA][i], cB = CL[locB][i];
                float4 h0 = *(const float4*)&HWL[i][d0];
                float4 h1 = *(const float4*)&HWL[i][d1];
                vA0.x = fmaf(cA, h0.x, vA0.x); vA0.y = fmaf(cA, h0.y, vA0.y);
                vA0.z = fmaf(cA, h0.z, vA0.z); vA0.w = fmaf(cA, h0.w, vA0.w);
                vA1.x = fmaf(cA, h1.x, vA1.x); vA1.y = fmaf(cA, h1.y, vA1.y);
                vA1.z = fmaf(cA, h1.z, vA1.z); vA1.w = fmaf(cA, h1.w, vA1.w);
                vB0.x = fmaf(cB, h0.x, vB0.x); vB0.y = fmaf(cB, h0.y, vB0.y);
                vB0.z = fmaf(cB, h0.z, vB0.z); vB0.w = fmaf(cB, h0.w, vB0.w);
                vB1.x = fmaf(cB, h1.x, vB1.x); vB1.y = fmaf(cB, h1.y, vB1.y);
                vB1.z = fmaf(cB, h1.z, vB1.z); vB1.w = fmaf(cB, h1.w, vB1.w);
            }
            *(float4*)(memOut + baseA + d0) = vA0;
            *(float4*)(memOut + baseA + d1) = vA1;
            *(float4*)(memOut + baseB + d0) = vB0;
            *(float4*)(memOut + baseB + d1) = vB1;
            uint2 sA0, sA1, sB0, sB1;
            sA0.x = (uint)f2b(vA0.x) | ((uint)f2b(vA0.y) << 16);
            sA0.y = (uint)f2b(vA0.z) | ((uint)f2b(vA0.w) << 16);
            sA1.x = (uint)f2b(vA1.x) | ((uint)f2b(vA1.y) << 16);
            sA1.y = (uint)f2b(vA1.z) | ((uint)f2b(vA1.w) << 16);
            sB0.x = (uint)f2b(vB0.x) | ((uint)f2b(vB0.y) << 16);
            sB0.y = (uint)f2b(vB0.z) | ((uint)f2b(vB0.w) << 16);
            sB1.x = (uint)f2b(vB1.x) | ((uint)f2b(vB1.y) << 16);
            sB1.y = (uint)f2b(vB1.z) | ((uint)f2b(vB1.w) << 16);
            *(uint2*)(mB16out + baseA + d0) = sA0;
            *(uint2*)(mB16out + baseA + d1) = sA1;
            *(uint2*)(mB16out + baseB + d0) = sB0;
            *(uint2*)(mB16out + baseB + d1) = sB1;
            float sa = vA0.x*oa.x + vA0.y*oa.y + vA0.z*oa.z + vA0.w*oa.w
                     + vA1.x*obv.x + vA1.y*obv.y + vA1.z*obv.z + vA1.w*obv.w;
            float sb = vB0.x*oa.x + vB0.y*oa.y + vB0.z*oa.z + vB0.w*oa.w
                     + vB1.x*obv.x + vB1.y*obv.y + vB1.z*obv.z + vB1.w*obv.w;
            #pragma unroll
            for (int off = 32; off; off >>= 1){
                sa += __shfl_xor(sa, off);
                sb += __shfl_xor(sb, off);
            }
            if (lane == 0){ srow[lbase + r] = sa; srow[lbase + 8 + r] = sb; }
            float nmA = fmaxf(mA, sa);
            float scA = __expf(mA - nmA);
            float wtA = __expf(sa - nmA);
            sAs = fmaf(sAs, scA, wtA);
            A0x = fmaf(A0x, scA, vA0.x * wtA); A0y = fmaf(A0y, scA, vA0.y * wtA);
            A0z = fmaf(A0z, scA, vA0.z * wtA); A0w = fmaf(A0w, scA, vA0.w * wtA);
            A1x = fmaf(A1x, scA, vA1.x * wtA); A1y = fmaf(A1y, scA, vA1.y * wtA);
            A1z = fmaf(A1z, scA, vA1.z * wtA); A1w = fmaf(A1w, scA, vA1.w * wtA);
            mA = nmA;
            float nmB = fmaxf(mB, sb);
            float scB = __expf(mB - nmB);
            float wtB = __expf(sb - nmB);
            sBs = fmaf(sBs, scB, wtB);
            B0x = fmaf(B0x, scB, vB0.x * wtB); B0y = fmaf(B0y, scB, vB0.y * wtB);
            B0z = fmaf(B0z, scB, vB0.z * wtB); B0w = fmaf(B0w, scB, vB0.w * wtB);
            B1x = fmaf(B1x, scB, vB1.x * wtB); B1y = fmaf(B1y, scB, vB1.y * wtB);
            B1z = fmaf(B1z, scB, vB1.z * wtB); B1w = fmaf(B1w, scB, vB1.w * wtB);
            mB = nmB;
            baseA += Dd; baseB += Dd;
        }
    } else {
        // FACTOR / PLAIN: stream bf16 shadow (half the bytes), convert in-register.
        #pragma unroll 2
        for (int r = 0; r < 8; ++r){
            const int locA = wvi * 16 + r, locB = locA + 8;
            uint2 qA0 = *(const uint2*)(mB16 + baseA + d0);
            uint2 qA1 = *(const uint2*)(mB16 + baseA + d1);
            uint2 qB0 = *(const uint2*)(mB16 + baseB + d0);
            uint2 qB1 = *(const uint2*)(mB16 + baseB + d1);
            float4 vA0 = make_float4(b2f(qA0.x & 0xffffu), b2f(qA0.x >> 16), b2f(qA0.y & 0xffffu), b2f(qA0.y >> 16));
            float4 vA1 = make_float4(b2f(qA1.x & 0xffffu), b2f(qA1.x >> 16), b2f(qA1.y & 0xffffu), b2f(qA1.y >> 16));
            float4 vB0 = make_float4(b2f(qB0.x & 0xffffu), b2f(qB0.x >> 16), b2f(qB0.y & 0xffffu), b2f(qB0.y >> 16));
            float4 vB1 = make_float4(b2f(qB1.x & 0xffffu), b2f(qB1.x >> 16), b2f(qB1.y & 0xffffu), b2f(qB1.y >> 16));
            float sa = vA0.x*oa.x + vA0.y*oa.y + vA0.z*oa.z + vA0.w*oa.w
                     + vA1.x*obv.x + vA1.y*obv.y + vA1.z*obv.z + vA1.w*obv.w;
            float sb = vB0.x*oa.x + vB0.y*oa.y + vB0.z*oa.z + vB0.w*oa.w
                     + vB1.x*obv.x + vB1.y*obv.y + vB1.z*obv.z + vB1.w*obv.w;
            #pragma unroll
            for (int off = 32; off; off >>= 1){
                sa += __shfl_xor(sa, off);
                sb += __shfl_xor(sb, off);
            }
            float DnA = 1.f, DnB = 1.f;
            if (mode == 2){
                DnA = DL[locA]; DnB = DL[locB];
                sa = fmaf(DnA, sa, CORRL[locA]);
                sb = fmaf(DnB, sb, CORRL[locB]);
            }
            if (lane == 0){ srow[lbase + r] = sa; srow[lbase + 8 + r] = sb; }
            if (lane == r)     my_s = sa;
            if (lane == 8 + r) my_s = sb;
            float nmA = fmaxf(mA, sa);
            float scA = __expf(mA - nmA);
            float wtA = __expf(sa - nmA);
            float wdA = wtA * DnA;
            sAs = fmaf(sAs, scA, wtA);
            A0x = fmaf(A0x, scA, vA0.x * wdA); A0y = fmaf(A0y, scA, vA0.y * wdA);
            A0z = fmaf(A0z, scA, vA0.z * wdA); A0w = fmaf(A0w, scA, vA0.w * wdA);
            A1x = fmaf(A1x, scA, vA1.x * wdA); A1y = fmaf(A1y, scA, vA1.y * wdA);
            A1z = fmaf(A1z, scA, vA1.z * wdA); A1w = fmaf(A1w, scA, vA1.w * wdA);
            mA = nmA;
            float nmB = fmaxf(mB, sb);
            float scB = __expf(mB - nmB);
            float wtB = __expf(sb - nmB);
            float wdB = wtB * DnB;
            sBs = fmaf(sBs, scB, wtB);
            B0x = fmaf(B0x, scB, vB0.x * wdB); B0y = fmaf(B0y, scB, vB0.y * wdB);
            B0z = fmaf(B0z, scB, vB0.z * wdB); B0w = fmaf(B0w, scB, vB0.w * wdB);
            B1x = fmaf(B1x, scB, vB1.x * wdB); B1y = fmaf(B1y, scB, vB1.y * wdB);
            B1z = fmaf(B1z, scB, vB1.z * wdB); B1w = fmaf(B1w, scB, vB1.w * wdB);
            mB = nmB;
            baseA += Dd; baseB += Dd;
        }
    }
    float M = fmaxf(mA, mB);
    float eA = __expf(mA - M), eB = __expf(mB - M);
    float ssum = sAs * eA + sBs * eB;
    float* pp = part + (size_t)(b * 64 + gw) * PART_STRIDE;
    *(float4*)(pp + d0) = make_float4(A0x * eA + B0x * eB, A0y * eA + B0y * eB,
                                      A0z * eA + B0z * eB, A0w * eA + B0w * eB);
    *(float4*)(pp + d1) = make_float4(A1x * eA + B1x * eB, A1y * eA + B1y * eB,
                                      A1z * eA + B1z * eB, A1w * eA + B1w * eB);
    if (lane == 0){ pp[512] = M; pp[513] = ssum; }
    if (mode == 2){
        float wexp = (lane < 16) ? __expf(my_s - M) : 0.f;
        float gacc = 0.f;
        const int ci = lane & 7;
        #pragma unroll
        for (int l = 0; l < 16; ++l){
            float wl = __shfl(wexp, l);
            gacc = fmaf(wl, CL[wvi * 16 + l][ci], gacc);
        }
        if (lane < 8) pp[514 + lane] = gacc;
    }
}

// ---------------- finalize: 64 wave partials -> m_rt (+ factored hw correction), M, 1/S ----------------
__global__ __launch_bounds__(256) void small_a(const float* __restrict__ part, float* __restrict__ mrt,
                                               float* __restrict__ Mb, float* __restrict__ Sinv,
                                               const float* __restrict__ hwring, int p){
    const int b = blockIdx.x >> 2, dseg = blockIdx.x & 3;
    const int tid = threadIdx.x;
    __shared__ float ews[64];
    __shared__ float psum[256];
    __shared__ float gam[KK][8];
    if (tid < 64){
        const float* pp = part + (size_t)(b * 64 + tid) * PART_STRIDE;
        float mw = pp[512], sw = pp[513];
        float M = mw;
        #pragma unroll
        for (int off = 32; off; off >>= 1) M = fmaxf(M, __shfl_xor(M, off));
        float e = __expf(mw - M);
        float Ssum = sw * e;
        #pragma unroll
        for (int off = 32; off; off >>= 1) Ssum += __shfl_xor(Ssum, off);
        float Si = 1.f / Ssum;
        ews[tid] = e * Si;
        if (dseg == 0 && tid == 0){ Mb[b] = M; Sinv[b] = Si; }
    }
    __syncthreads();
    if (p > 0 && tid < 64){
        const int i = tid & 7, ch = tid >> 3;
        float s = 0.f;
        #pragma unroll
        for (int w2 = 0; w2 < 8; ++w2)
            s = fmaf(part[(size_t)(b * 64 + ch * 8 + w2) * PART_STRIDE + 514 + i], ews[ch * 8 + w2], s);
        gam[i][ch] = s;
    }
    __syncthreads();
    if (p > 0 && tid < 8){
        float s = gam[tid][0];
        #pragma unroll
        for (int ch = 1; ch < 8; ++ch) s += gam[tid][ch];
        gam[tid][0] = s;
    }
    const int dl = tid & 127, half = tid >> 7;
    const int d = dseg * 128 + dl;
    const float* pb = part + (size_t)(b * 64 + half * 32) * PART_STRIDE + d;
    float s = 0.f;
    #pragma unroll 8
    for (int w2 = 0; w2 < 32; ++w2)
        s = fmaf(pb[(size_t)w2 * PART_STRIDE], ews[half * 32 + w2], s);
    psum[tid] = s;
    __syncthreads();
    if (half == 0){
        float r = psum[tid] + psum[tid + 128];
        for (int i = 0; i < p; ++i)
            r = fmaf(gam[i][0], hwring[((size_t)i * Bb + b) * Dd + d], r);
        mrt[b * Dd + d] = r;
    }
}

extern "C" void kernel_launch(void* const* d_in, const int* in_sizes, int n_in,
                              void* d_out, int out_size, void* d_ws, size_t ws_size,
                              hipStream_t stream) {
    (void)in_sizes; (void)n_in; (void)out_size;
    const float* x  = (const float*)d_in[0];
    const float* Wr = (const float*)d_in[1];
    const float* Ur = (const float*)d_in[2];
    const float* br = (const float*)d_in[3];
    const float* Ww = (const float*)d_in[4];
    const float* Uw = (const float*)d_in[5];
    const float* bw = (const float*)d_in[6];
    const float* Wc = (const float*)d_in[7];
    const float* bc = (const float*)d_in[8];
    float* out = (float*)d_out;

    float* w = (float*)d_ws;
    float* mem     = w; w += (size_t)Bb * Ll * Dd;
    ushort* memB16 = (ushort*)w; w += (size_t)Bb * Ll * Dd / 2;   // bf16 shadow (67 MB)
    float* scores  = w; w += (size_t)Bb * Ll;
    float* part_me = w; w += (size_t)Bb * 64 * PART_STRIDE;
    float* Mb      = w; w += 64;
    float* Sinv    = w; w += 64;
    float* mrt     = w; w += (size_t)Bb * Dd;
    float* Dv      = w; w += (size_t)Bb * Ll;
    float* Cv      = w; w += (size_t)Bb * Ll * KK;
    float* h_r     = w; w += (size_t)Bb * Dd;     // memset region: h_r,c_r,cw,hwring
    float* c_r     = w; w += (size_t)Bb * Dd;
    float* cw      = w; w += (size_t)Bb * Dd;
    float* hwring  = w; w += (size_t)KK * Bb * Dd;
    float* partR   = w; w += (size_t)RSL * Bb * G4;
    float* partW   = w; w += (size_t)WSL * Bb * G4;
    float* Wf      = w; w += (size_t)1536 * G4;
    float* bf      = w; w += G4;
    size_t need = (size_t)(w - (float*)d_ws) * sizeof(float);
    if (ws_size < need) return;

    hipMemsetAsync(h_r, 0, (size_t)(3 + KK) * Bb * Dd * sizeof(float), stream);
    wf_build<<<(1536 / 16) * 8, 256, 0, stream>>>(Wc, Ww, Uw, Wf);
    bf_build<<<G4 / 256, 256, 0, stream>>>(bc, Ww, bw, bf);
    conv_b<<<(Bb * Ll * Dd) / (256 * 8), 256, 0, stream>>>(x, memB16);

    // prologue: reader step 0
    gemm_reader<<<256, 256, 0, stream>>>(x, h_r, Wr, Ur, partR);
    reader_pw<<<128, 256, 0, stream>>>(partR, br, h_r, c_r);

    for (int t = 0; t < Ll; ++t){
        const int p = t & (KK - 1);
        const int mode = (t == 0) ? 0 : ((p == 0) ? 1 : 2);
        const float* mi = (t <= KK) ? x : mem;   // MAT reads fp32 x/mem; FACTOR reads bf16 shadow
        mega3<<<1024, 256, 0, stream>>>(mi, mem, memB16, memB16, h_r, scores, Mb, Sinv, part_me,
                                        Dv, Cv, hwring, mode, p);
        small_a<<<256, 256, 0, stream>>>(part_me, mrt, Mb, Sinv, hwring, (mode == 2) ? p : 0);
        int tn = (t + 1 < Ll) ? t + 1 : t;
        const float* hwprev = hwring + ((size_t)((t + KK - 1) & (KK - 1)) * Bb) * Dd;
        gemm_fast<<<(WSL + RSL) * 64, 256, 0, stream>>>(h_r, mrt, hwprev, Wf, partW,
                                                        x + (size_t)tn * Dd, Wr, Ur, partR);
        float* hwnew = hwring + ((size_t)(t & (KK - 1)) * Bb) * Dd;
        pw_both<<<256, 256, 0, stream>>>(partW, bf, hwnew, cw, out, t == Ll - 1 ? 1 : 0,
                                         partR, br, h_r, c_r);
    }
}

// Round 17
// 68683.374 us; speedup vs baseline: 1.1656x; 1.0071x over previous
//
#include <hip/hip_runtime.h>
#include <math.h>

#define Bb 64
#define Ll 1024
#define Dd 512
#define G4 2048        // 4*D
#define KK 8           // factor-block length
#define PART_STRIDE 524  // 512 acc + m + ssum + 8 gamma + pad
#define WSL 12         // writer K-slices (12 x 128 = 1536)
#define RSL 8          // reader K-slices (8 x 128 = 1024)

__device__ __forceinline__ float hsig(float v){ return fminf(fmaxf(0.2f*v + 0.5f, 0.f), 1.f); }

// ---------------- one-time: Wf = [Wc@Ww ; Uw]  (1536 x 2048), bf = bc@Ww + bw ----------------
__global__ __launch_bounds__(256) void wf_build(const float* __restrict__ Wc, const float* __restrict__ Ww,
                                                const float* __restrict__ Uw, float* __restrict__ Wf){
    const int k0 = (blockIdx.x >> 3) * 16;
    const int j  = (blockIdx.x & 7) * 256 + threadIdx.x;
    if (k0 < 2 * Dd){
        float acc[16];
        #pragma unroll
        for (int kk = 0; kk < 16; ++kk) acc[kk] = 0.f;
        for (int m = 0; m < Dd; ++m){
            float wv = Ww[(size_t)m * G4 + j];
            #pragma unroll
            for (int kk = 0; kk < 16; ++kk)
                acc[kk] = fmaf(Wc[(size_t)(k0 + kk) * Dd + m], wv, acc[kk]);
        }
        #pragma unroll
        for (int kk = 0; kk < 16; ++kk) Wf[(size_t)(k0 + kk) * G4 + j] = acc[kk];
    } else {
        #pragma unroll
        for (int kk = 0; kk < 16; ++kk)
            Wf[(size_t)(k0 + kk) * G4 + j] = Uw[(size_t)(k0 + kk - 2 * Dd) * G4 + j];
    }
}

__global__ __launch_bounds__(256) void bf_build(const float* __restrict__ bc, const float* __restrict__ Ww,
                                                const float* __restrict__ bw, float* __restrict__ bf){
    int j = blockIdx.x * 256 + threadIdx.x;
    float s = bw[j];
    for (int m = 0; m < Dd; ++m) s = fmaf(bc[m], Ww[(size_t)m * G4 + j], s);
    bf[j] = s;
}

// ---------------- reader gate GEMM (prologue t=0 only; 4-slice layout matched with reader_pw) ----------------
__global__ __launch_bounds__(256) void gemm_reader(const float* __restrict__ xt, const float* __restrict__ h,
                                                   const float* __restrict__ Wr, const float* __restrict__ Ur,
                                                   float* __restrict__ part){
    __shared__ float inT[64][65];
    __shared__ float wT[64][32];
    const int bx = blockIdx.x;
    const int jt = bx & 63, ks = bx >> 6;
    const int j0 = jt * 32;
    const int k0 = ks * 256;
    const int tid = threadIdx.x;
    const int tj4 = (tid & 7) * 4;
    const int tb  = tid >> 3;
    float a00=0.f,a01=0.f,a02=0.f,a03=0.f;
    float a10=0.f,a11=0.f,a12=0.f,a13=0.f;
    for (int kk = 0; kk < 256; kk += 64){
        #pragma unroll
        for (int i = 0; i < 16; ++i){
            int idx = tid + i * 256;
            int b = idx >> 6, k = idx & 63;
            int kg = k0 + kk + k;
            inT[b][k] = (kg < Dd) ? xt[(size_t)b * (Ll * Dd) + kg] : h[b * Dd + kg - Dd];
        }
        #pragma unroll
        for (int i = 0; i < 8; ++i){
            int idx = tid + i * 256;
            int k = idx >> 5, j = idx & 31;
            int kg = k0 + kk + k;
            wT[k][j] = (kg < Dd) ? Wr[(size_t)kg * G4 + j0 + j] : Ur[(size_t)(kg - Dd) * G4 + j0 + j];
        }
        __syncthreads();
        #pragma unroll 8
        for (int k = 0; k < 64; ++k){
            float4 wv = *(const float4*)&wT[k][tj4];
            float i0 = inT[tb][k];
            float i1 = inT[tb + 32][k];
            a00 = fmaf(i0, wv.x, a00); a01 = fmaf(i0, wv.y, a01);
            a02 = fmaf(i0, wv.z, a02); a03 = fmaf(i0, wv.w, a03);
            a10 = fmaf(i1, wv.x, a10); a11 = fmaf(i1, wv.y, a11);
            a12 = fmaf(i1, wv.z, a12); a13 = fmaf(i1, wv.w, a13);
        }
        __syncthreads();
    }
    size_t o0 = (size_t)(ks * Bb + tb) * G4 + j0 + tj4;
    size_t o1 = (size_t)(ks * Bb + tb + 32) * G4 + j0 + tj4;
    *(float4*)&part[o0] = make_float4(a00, a01, a02, a03);
    *(float4*)&part[o1] = make_float4(a10, a11, a12, a13);
}

__global__ __launch_bounds__(256) void reader_pw(const float* __restrict__ part, const float* __restrict__ br,
                                                 float* __restrict__ h, float* __restrict__ c){
    int idx = blockIdx.x * 256 + threadIdx.x;
    int b = idx >> 9, d = idx & 511;
    float z[4];
    #pragma unroll
    for (int g = 0; g < 4; ++g){
        int j = g * Dd + d;
        float s = br[j];
        #pragma unroll
        for (int ks = 0; ks < 4; ++ks) s += part[(size_t)(ks * Bb + b) * G4 + j];
        z[g] = s;
    }
    float i = hsig(z[0]), f = hsig(z[1]), g2 = tanhf(z[2]), o = hsig(z[3]);
    float cn = fmaf(f, c[idx], i * g2);
    c[idx] = cn;
    h[idx] = o * tanhf(cn);
}

// ---------------- gemm_fast: double-buffered, float4-staged step GEMM ----------------
// grid 1280: [0,768) writer (12 ks x 64 jt, K=1536), [768,1280) reader (8 ks x 64 jt, K=1024).
// Block: 64M x 32N, K-chunk 128 = 2 subtiles of 64. 2 barriers total; prefetch overlaps compute.
__global__ __launch_bounds__(256) void gemm_fast(const float* __restrict__ o, const float* __restrict__ mrt,
                                                 const float* __restrict__ hw, const float* __restrict__ Wf,
                                                 float* __restrict__ partW,
                                                 const float* __restrict__ xt1, const float* __restrict__ Wr,
                                                 const float* __restrict__ Ur, float* __restrict__ partR){
    __shared__ float inT[2][64][68];
    __shared__ float wT[2][64][36];
    const int bxg = blockIdx.x;
    const bool writer = (bxg < WSL * 64);
    const int bx = writer ? bxg : bxg - WSL * 64;
    const int jt = bx & 63;
    const int ks = bx >> 6;
    const int j0 = jt * 32;
    const int k0 = ks * 128;
    const int tid = threadIdx.x;
    const int tj4 = (tid & 7) * 4;
    const int tb  = tid >> 3;

    float4 aR0, aR1, aR2, aR3, wR0, wR1;
    auto LOAD = [&](int kk){
        #pragma unroll
        for (int i = 0; i < 4; ++i){
            int lin = tid + i * 256;
            int b = lin >> 4, k4 = (lin & 15) * 4;
            int kg = k0 + kk + k4;
            const float* src;
            if (writer){
                if (kg < Dd)           src = o   + b * Dd + kg;
                else if (kg < 2 * Dd)  src = mrt + b * Dd + kg - Dd;
                else                   src = hw  + b * Dd + kg - 2 * Dd;
            } else {
                src = (kg < Dd) ? xt1 + (size_t)b * (Ll * Dd) + kg
                                : o + b * Dd + kg - Dd;
            }
            float4 v = *(const float4*)src;
            if (i == 0) aR0 = v; else if (i == 1) aR1 = v; else if (i == 2) aR2 = v; else aR3 = v;
        }
        #pragma unroll
        for (int i = 0; i < 2; ++i){
            int lin = tid + i * 256;
            int k = lin >> 3, j4 = (lin & 7) * 4;
            int kg = k0 + kk + k;
            const float* src;
            if (writer) src = Wf + (size_t)kg * G4 + j0 + j4;
            else        src = (kg < Dd) ? Wr + (size_t)kg * G4 + j0 + j4
                                        : Ur + (size_t)(kg - Dd) * G4 + j0 + j4;
            float4 v = *(const float4*)src;
            if (i == 0) wR0 = v; else wR1 = v;
        }
    };
    auto STORE = [&](int buf){
        #pragma unroll
        for (int i = 0; i < 4; ++i){
            int lin = tid + i * 256;
            int b = lin >> 4, k4 = (lin & 15) * 4;
            float4 v = (i == 0) ? aR0 : (i == 1) ? aR1 : (i == 2) ? aR2 : aR3;
            *(float4*)&inT[buf][b][k4] = v;
        }
        #pragma unroll
        for (int i = 0; i < 2; ++i){
            int lin = tid + i * 256;
            int k = lin >> 3, j4 = (lin & 7) * 4;
            float4 v = (i == 0) ? wR0 : wR1;
            *(float4*)&wT[buf][k][j4] = v;
        }
    };

    float a00=0.f,a01=0.f,a02=0.f,a03=0.f;
    float a10=0.f,a11=0.f,a12=0.f,a13=0.f;

    LOAD(0);
    STORE(0);
    __syncthreads();
    LOAD(64);                       // prefetch subtile 1 (in flight during compute 0)
    #pragma unroll 8
    for (int k = 0; k < 64; ++k){
        float4 wv = *(const float4*)&wT[0][k][tj4];
        float i0 = inT[0][tb][k];
        float i1 = inT[0][tb + 32][k];
        a00 = fmaf(i0, wv.x, a00); a01 = fmaf(i0, wv.y, a01);
        a02 = fmaf(i0, wv.z, a02); a03 = fmaf(i0, wv.w, a03);
        a10 = fmaf(i1, wv.x, a10); a11 = fmaf(i1, wv.y, a11);
        a12 = fmaf(i1, wv.z, a12); a13 = fmaf(i1, wv.w, a13);
    }
    STORE(1);
    __syncthreads();
    #pragma unroll 8
    for (int k = 0; k < 64; ++k){
        float4 wv = *(const float4*)&wT[1][k][tj4];
        float i0 = inT[1][tb][k];
        float i1 = inT[1][tb + 32][k];
        a00 = fmaf(i0, wv.x, a00); a01 = fmaf(i0, wv.y, a01);
        a02 = fmaf(i0, wv.z, a02); a03 = fmaf(i0, wv.w, a03);
        a10 = fmaf(i1, wv.x, a10); a11 = fmaf(i1, wv.y, a11);
        a12 = fmaf(i1, wv.z, a12); a13 = fmaf(i1, wv.w, a13);
    }
    float* part = writer ? partW : partR;
    size_t o0 = (size_t)(ks * Bb + tb) * G4 + j0 + tj4;
    size_t o1 = (size_t)(ks * Bb + tb + 32) * G4 + j0 + tj4;
    *(float4*)&part[o0] = make_float4(a00, a01, a02, a03);
    *(float4*)&part[o1] = make_float4(a10, a11, a12, a13);
}

// ---------------- FUSED PW: blocks [0,128) = writer_pw(t) [12 slices], [128,256) = reader_pw(t+1) [8] ----------------
__global__ __launch_bounds__(256) void pw_both(const float* __restrict__ partW, const float* __restrict__ bfv,
                                               float* __restrict__ hw, float* __restrict__ cw,
                                               float* __restrict__ out, int last,
                                               const float* __restrict__ partR, const float* __restrict__ br,
                                               float* __restrict__ h, float* __restrict__ c){
    const int bxg = blockIdx.x;
    const int writer = (bxg < 128) ? 1 : 0;
    const int idx = (writer ? bxg : bxg - 128) * 256 + threadIdx.x;
    const int b = idx >> 9, d = idx & 511;
    float z[4];
    #pragma unroll
    for (int g = 0; g < 4; ++g){
        int j = g * Dd + d;
        float s;
        if (writer){
            s = bfv[j];
            #pragma unroll
            for (int sl = 0; sl < WSL; ++sl) s += partW[(size_t)(sl * Bb + b) * G4 + j];
        } else {
            s = br[j];
            #pragma unroll
            for (int sl = 0; sl < RSL; ++sl) s += partR[(size_t)(sl * Bb + b) * G4 + j];
        }
        z[g] = s;
    }
    float i = hsig(z[0]), f = hsig(z[1]), g2 = tanhf(z[2]), o = hsig(z[3]);
    if (writer){
        float cn = fmaf(f, cw[idx], i * g2);
        cw[idx] = cn;
        float hn = o * tanhf(cn);
        hw[idx] = hn;
        if (last) out[idx] = hn;
    } else {
        float cn = fmaf(f, c[idx], i * g2);
        c[idx] = cn;
        h[idx] = o * tanhf(cn);
    }
}

// ---------------- MEGA3: factored attention pass (R9/R13, verified) ----------------
// mem_t[l] = D_l * memB_l + sum_i c_{l,i} * hw_i  (block of KK steps)
// mode 0: t==0 plain pass. mode 2 (FACTOR): D/c prologue + corrected scores + factored read (no stores).
// mode 1 (MAT): reconstruct + write memB.
__global__ __launch_bounds__(256, 4) void mega3(const float* memB, float* memOut,
                                                const float* __restrict__ o,
                                                float* __restrict__ scores, const float* __restrict__ Mb,
                                                const float* __restrict__ Sinv,
                                                float* __restrict__ part,
                                                float* __restrict__ Dv, float* __restrict__ Cv,
                                                const float* __restrict__ hwring,
                                                int mode, int p){
    __shared__ float DL[64];
    __shared__ float CORRL[64];
    __shared__ float CL[64][KK];
    __shared__ float GL[KK];
    __shared__ float HWL[KK][Dd];
    const int bid = blockIdx.x;
    const int b = bid >> 4, lb = bid & 15;
    const int tid = threadIdx.x;
    const int lane = tid & 63;
    const int wvi = tid >> 6;
    const int gw = lb * 4 + wvi;
    const int d0 = lane * 4, d1 = 256 + lane * 4;

    if (mode == 2){
        for (int ii = wvi; ii < p; ii += 4){
            const float* ov = o + b * Dd + lane * 8;
            const float* hv = hwring + ((size_t)ii * Bb + b) * Dd + lane * 8;
            float4 x0 = *(const float4*)ov;
            float4 x1 = *(const float4*)(ov + 4);
            float4 y0 = *(const float4*)hv;
            float4 y1 = *(const float4*)(hv + 4);
            float s = x0.x*y0.x + x0.y*y0.y + x0.z*y0.z + x0.w*y0.w
                    + x1.x*y1.x + x1.y*y1.y + x1.z*y1.z + x1.w*y1.w;
            #pragma unroll
            for (int off = 32; off; off >>= 1) s += __shfl_xor(s, off);
            if (lane == 0) GL[ii] = s;
        }
        __syncthreads();
    }

    if (mode){
        if (tid < 64){
            const int l = lb * 64 + tid;
            const size_t cbase = (size_t)(b * Ll + l) * KK;
            float z = __expf(scores[b * Ll + l] - Mb[b]) * Sinv[b];
            float om = 1.f - z;
            const int pm1 = (mode == 1) ? (KK - 1) : (p - 1);
            float cl[KK];
            float Dn;
            if (pm1 == 0){
                Dn = om;
                #pragma unroll
                for (int i = 0; i < KK; ++i) cl[i] = 0.f;
            } else {
                Dn = Dv[b * Ll + l] * om;
                #pragma unroll
                for (int i = 0; i < KK; ++i) cl[i] = Cv[cbase + i] * om;
                #pragma unroll
                for (int i = 0; i < KK; ++i) if (i > pm1) cl[i] = 0.f;
            }
            cl[pm1] = z;
            DL[tid] = Dn;
            #pragma unroll
            for (int i = 0; i < KK; ++i) CL[tid][i] = cl[i];
            if (mode == 2){
                Dv[b * Ll + l] = Dn;
                #pragma unroll
                for (int i = 0; i < KK; ++i) Cv[cbase + i] = cl[i];
                float corr = 0.f;
                #pragma unroll
                for (int i = 0; i < KK; ++i) corr = fmaf(cl[i], (i < p) ? GL[i] : 0.f, corr);
                CORRL[tid] = corr;
            }
        }
        if (mode == 1){
            for (int i = tid; i < KK * Dd; i += 256){
                int s = i >> 9, d = i & 511;
                HWL[s][d] = hwring[((size_t)s * Bb + b) * Dd + d];
            }
        }
        __syncthreads();
    }

    float4 oa  = *(const float4*)(o + b * Dd + d0);
    float4 obv = *(const float4*)(o + b * Dd + d1);
    const int lbase = gw * 16;
    float* srow = scores + b * Ll;

    float mA = -INFINITY, sAs = 0.f, mB = -INFINITY, sBs = 0.f;
    float A0x=0.f,A0y=0.f,A0z=0.f,A0w=0.f, A1x=0.f,A1y=0.f,A1z=0.f,A1w=0.f;
    float B0x=0.f,B0y=0.f,B0z=0.f,B0w=0.f, B1x=0.f,B1y=0.f,B1z=0.f,B1w=0.f;
    float my_s = 0.f;
    size_t baseA = ((size_t)b * Ll + lbase) * Dd;
    size_t baseB = baseA + (size_t)8 * Dd;

    if (mode == 1){
        #pragma unroll 2
        for (int r = 0; r < 8; ++r){
            const int locA = wvi * 16 + r, locB = locA + 8;
            float4 vA0 = *(const float4*)(memB + baseA + d0);
            float4 vA1 = *(const float4*)(memB + baseA + d1);
            float4 vB0 = *(const float4*)(memB + baseB + d0);
            float4 vB1 = *(const float4*)(memB + baseB + d1);
            float DnA = DL[locA], DnB = DL[locB];
            vA0.x *= DnA; vA0.y *= DnA; vA0.z *= DnA; vA0.w *= DnA;
            vA1.x *= DnA; vA1.y *= DnA; vA1.z *= DnA; vA1.w *= DnA;
            vB0.x *= DnB; vB0.y *= DnB; vB0.z *= DnB; vB0.w *= DnB;
            vB1.x *= DnB; vB1.y *= DnB; vB1.z *= DnB; vB1.w *= DnB;
            #pragma unroll
            for (int i = 0; i < KK; ++i){
                float cA = CL[locA][i], cB = CL[locB][i];
                float4 h0 = *(const float4*)&HWL[i][d0];
                float4 h1 = *(const float4*)&HWL[i][d1];
                vA0.x = fmaf(cA, h0.x, vA0.x); vA0.y = fmaf(cA, h0.y, vA0.y);
                vA0.z = fmaf(cA, h0.z, vA0.z); vA0.w = fmaf(cA, h0.w, vA0.w);
                vA1.x = fmaf(cA, h1.x, vA1.x); vA1.y = fmaf(cA, h1.y, vA1.y);
                vA1.z = fmaf(cA, h1.z, vA1.z); vA1.w = fmaf(cA, h1.w, vA1.w);
                vB0.x = fmaf(cB, h0.x, vB0.x); vB0.y = fmaf(cB, h0.y, vB0.y);
                vB0.z = fmaf(cB, h0.z, vB0.z); vB0.w = fmaf(cB, h0.w, vB0.w);
                vB1.x = fmaf(cB, h1.x, vB1.x); vB1.y = fmaf(cB, h1.y, vB1.y);
                vB1.z = fmaf(cB, h1.z, vB1.z); vB1.w = fmaf(cB, h1.w, vB1.w);
            }
            *(float4*)(memOut + baseA + d0) = vA0;
            *(float4*)(memOut + baseA + d1) = vA1;
            *(float4*)(memOut + baseB + d0) = vB0;
            *(float4*)(memOut + baseB + d1) = vB1;
            float sa = vA0.x*oa.x + vA0.y*oa.y + vA0.z*oa.z + vA0.w*oa.w
                     + vA1.x*obv.x + vA1.y*obv.y + vA1.z*obv.z + vA1.w*obv.w;
            float sb = vB0.x*oa.x + vB0.y*oa.y + vB0.z*oa.z + vB0.w*oa.w
                     + vB1.x*obv.x + vB1.y*obv.y + vB1.z*obv.z + vB1.w*obv.w;
            #pragma unroll
            for (int off = 32; off; off >>= 1){
                sa += __shfl_xor(sa, off);
                sb += __shfl_xor(sb, off);
            }
            if (lane == 0){ srow[lbase + r] = sa; srow[lbase + 8 + r] = sb; }
            float nmA = fmaxf(mA, sa);
            float scA = __expf(mA - nmA);
            float wtA = __expf(sa - nmA);
            sAs = fmaf(sAs, scA, wtA);
            A0x = fmaf(A0x, scA, vA0.x * wtA); A0y = fmaf(A0y, scA, vA0.y * wtA);
            A0z = fmaf(A0z, scA, vA0.z * wtA); A0w = fmaf(A0w, scA, vA0.w * wtA);
            A1x = fmaf(A1x, scA, vA1.x * wtA); A1y = fmaf(A1y, scA, vA1.y * wtA);
            A1z = fmaf(A1z, scA, vA1.z * wtA); A1w = fmaf(A1w, scA, vA1.w * wtA);
            mA = nmA;
            float nmB = fmaxf(mB, sb);
            float scB = __expf(mB - nmB);
            float wtB = __expf(sb - nmB);
            sBs = fmaf(sBs, scB, wtB);
            B0x = fmaf(B0x, scB, vB0.x * wtB); B0y = fmaf(B0y, scB, vB0.y * wtB);
            B0z = fmaf(B0z, scB, vB0.z * wtB); B0w = fmaf(B0w, scB, vB0.w * wtB);
            B1x = fmaf(B1x, scB, vB1.x * wtB); B1y = fmaf(B1y, scB, vB1.y * wtB);
            B1z = fmaf(B1z, scB, vB1.z * wtB); B1w = fmaf(B1w, scB, vB1.w * wtB);
            mB = nmB;
            baseA += Dd; baseB += Dd;
        }
    } else {
        // FACTOR / PLAIN: pure streaming read + score + softmax-read. No stores, no in-loop gamma.
        #pragma unroll 2
        for (int r = 0; r < 8; ++r){
            const int locA = wvi * 16 + r, locB = locA + 8;
            float4 vA0 = *(const float4*)(memB + baseA + d0);
            float4 vA1 = *(const float4*)(memB + baseA + d1);
            float4 vB0 = *(const float4*)(memB + baseB + d0);
            float4 vB1 = *(const float4*)(memB + baseB + d1);
            float sa = vA0.x*oa.x + vA0.y*oa.y + vA0.z*oa.z + vA0.w*oa.w
                     + vA1.x*obv.x + vA1.y*obv.y + vA1.z*obv.z + vA1.w*obv.w;
            float sb = vB0.x*oa.x + vB0.y*oa.y + vB0.z*oa.z + vB0.w*oa.w
                     + vB1.x*obv.x + vB1.y*obv.y + vB1.z*obv.z + vB1.w*obv.w;
            #pragma unroll
            for (int off = 32; off; off >>= 1){
                sa += __shfl_xor(sa, off);
                sb += __shfl_xor(sb, off);
            }
            float DnA = 1.f, DnB = 1.f;
            if (mode == 2){
                DnA = DL[locA]; DnB = DL[locB];
                sa = fmaf(DnA, sa, CORRL[locA]);
                sb = fmaf(DnB, sb, CORRL[locB]);
            }
            if (lane == 0){ srow[lbase + r] = sa; srow[lbase + 8 + r] = sb; }
            if (lane == r)     my_s = sa;
            if (lane == 8 + r) my_s = sb;
            float nmA = fmaxf(mA, sa);
            float scA = __expf(mA - nmA);
            float wtA = __expf(sa - nmA);
            float wdA = wtA * DnA;
            sAs = fmaf(sAs, scA, wtA);
            A0x = fmaf(A0x, scA, vA0.x * wdA); A0y = fmaf(A0y, scA, vA0.y * wdA);
            A0z = fmaf(A0z, scA, vA0.z * wdA); A0w = fmaf(A0w, scA, vA0.w * wdA);
            A1x = fmaf(A1x, scA, vA1.x * wdA); A1y = fmaf(A1y, scA, vA1.y * wdA);
            A1z = fmaf(A1z, scA, vA1.z * wdA); A1w = fmaf(A1w, scA, vA1.w * wdA);
            mA = nmA;
            float nmB = fmaxf(mB, sb);
            float scB = __expf(mB - nmB);
            float wtB = __expf(sb - nmB);
            float wdB = wtB * DnB;
            sBs = fmaf(sBs, scB, wtB);
            B0x = fmaf(B0x, scB, vB0.x * wdB); B0y = fmaf(B0y, scB, vB0.y * wdB);
            B0z = fmaf(B0z, scB, vB0.z * wdB); B0w = fmaf(B0w, scB, vB0.w * wdB);
            B1x = fmaf(B1x, scB, vB1.x * wdB); B1y = fmaf(B1y, scB, vB1.y * wdB);
            B1z = fmaf(B1z, scB, vB1.z * wdB); B1w = fmaf(B1w, scB, vB1.w * wdB);
            mB = nmB;
            baseA += Dd; baseB += Dd;
        }
    }
    float M = fmaxf(mA, mB);
    float eA = __expf(mA - M), eB = __expf(mB - M);
    float ssum = sAs * eA + sBs * eB;
    float* pp = part + (size_t)(b * 64 + gw) * PART_STRIDE;
    *(float4*)(pp + d0) = make_float4(A0x * eA + B0x * eB, A0y * eA + B0y * eB,
                                      A0z * eA + B0z * eB, A0w * eA + B0w * eB);
    *(float4*)(pp + d1) = make_float4(A1x * eA + B1x * eB, A1y * eA + B1y * eB,
                                      A1z * eA + B1z * eB, A1w * eA + B1w * eB);
    if (lane == 0){ pp[512] = M; pp[513] = ssum; }
    if (mode == 2){
        // gamma_i = sum_r exp(s_r - M) * c_{r,i}, recomputed post-loop (no loop-carried regs)
        float wexp = (lane < 16) ? __expf(my_s - M) : 0.f;
        float gacc = 0.f;
        const int ci = lane & 7;
        #pragma unroll
        for (int l = 0; l < 16; ++l){
            float wl = __shfl(wexp, l);
            gacc = fmaf(wl, CL[wvi * 16 + l][ci], gacc);
        }
        if (lane < 8) pp[514 + lane] = gacc;
    }
}

// ---------------- finalize: 64 wave partials -> m_rt (+ factored hw correction), M, 1/S ----------------
__global__ __launch_bounds__(256) void small_a(const float* __restrict__ part, float* __restrict__ mrt,
                                               float* __restrict__ Mb, float* __restrict__ Sinv,
                                               const float* __restrict__ hwring, int p){
    const int b = blockIdx.x >> 2, dseg = blockIdx.x & 3;
    const int tid = threadIdx.x;
    __shared__ float ews[64];
    __shared__ float psum[256];
    __shared__ float gam[KK][8];
    if (tid < 64){
        const float* pp = part + (size_t)(b * 64 + tid) * PART_STRIDE;
        float mw = pp[512], sw = pp[513];
        float M = mw;
        #pragma unroll
        for (int off = 32; off; off >>= 1) M = fmaxf(M, __shfl_xor(M, off));
        float e = __expf(mw - M);
        float Ssum = sw * e;
        #pragma unroll
        for (int off = 32; off; off >>= 1) Ssum += __shfl_xor(Ssum, off);
        float Si = 1.f / Ssum;
        ews[tid] = e * Si;
        if (dseg == 0 && tid == 0){ Mb[b] = M; Sinv[b] = Si; }
    }
    __syncthreads();
    if (p > 0 && tid < 64){
        const int i = tid & 7, ch = tid >> 3;
        float s = 0.f;
        #pragma unroll
        for (int w2 = 0; w2 < 8; ++w2)
            s = fmaf(part[(size_t)(b * 64 + ch * 8 + w2) * PART_STRIDE + 514 + i], ews[ch * 8 + w2], s);
        gam[i][ch] = s;
    }
    __syncthreads();
    if (p > 0 && tid < 8){
        float s = gam[tid][0];
        #pragma unroll
        for (int ch = 1; ch < 8; ++ch) s += gam[tid][ch];
        gam[tid][0] = s;
    }
    const int dl = tid & 127, half = tid >> 7;
    const int d = dseg * 128 + dl;
    const float* pb = part + (size_t)(b * 64 + half * 32) * PART_STRIDE + d;
    float s = 0.f;
    #pragma unroll 8
    for (int w2 = 0; w2 < 32; ++w2)
        s = fmaf(pb[(size_t)w2 * PART_STRIDE], ews[half * 32 + w2], s);
    psum[tid] = s;
    __syncthreads();
    if (half == 0){
        float r = psum[tid] + psum[tid + 128];
        for (int i = 0; i < p; ++i)
            r = fmaf(gam[i][0], hwring[((size_t)i * Bb + b) * Dd + d], r);
        mrt[b * Dd + d] = r;
    }
}

extern "C" void kernel_launch(void* const* d_in, const int* in_sizes, int n_in,
                              void* d_out, int out_size, void* d_ws, size_t ws_size,
                              hipStream_t stream) {
    (void)in_sizes; (void)n_in; (void)out_size;
    const float* x  = (const float*)d_in[0];
    const float* Wr = (const float*)d_in[1];
    const float* Ur = (const float*)d_in[2];
    const float* br = (const float*)d_in[3];
    const float* Ww = (const float*)d_in[4];
    const float* Uw = (const float*)d_in[5];
    const float* bw = (const float*)d_in[6];
    const float* Wc = (const float*)d_in[7];
    const float* bc = (const float*)d_in[8];
    float* out = (float*)d_out;

    float* w = (float*)d_ws;
    float* mem     = w; w += (size_t)Bb * Ll * Dd;
    float* scores  = w; w += (size_t)Bb * Ll;
    float* part_me = w; w += (size_t)Bb * 64 * PART_STRIDE;
    float* Mb      = w; w += 64;
    float* Sinv    = w; w += 64;
    float* mrt     = w; w += (size_t)Bb * Dd;
    float* Dv      = w; w += (size_t)Bb * Ll;
    float* Cv      = w; w += (size_t)Bb * Ll * KK;
    float* h_r     = w; w += (size_t)Bb * Dd;     // memset region: h_r,c_r,cw,hwring
    float* c_r     = w; w += (size_t)Bb * Dd;
    float* cw      = w; w += (size_t)Bb * Dd;
    float* hwring  = w; w += (size_t)KK * Bb * Dd;
    float* partR   = w; w += (size_t)RSL * Bb * G4;
    float* partW   = w; w += (size_t)WSL * Bb * G4;
    float* Wf      = w; w += (size_t)1536 * G4;
    float* bf      = w; w += G4;
    size_t need = (size_t)(w - (float*)d_ws) * sizeof(float);
    if (ws_size < need) return;

    hipMemsetAsync(h_r, 0, (size_t)(3 + KK) * Bb * Dd * sizeof(float), stream);
    wf_build<<<(1536 / 16) * 8, 256, 0, stream>>>(Wc, Ww, Uw, Wf);
    bf_build<<<G4 / 256, 256, 0, stream>>>(bc, Ww, bw, bf);

    // prologue: reader step 0 (4-slice layout, matched gemm_reader/reader_pw pair)
    gemm_reader<<<256, 256, 0, stream>>>(x, h_r, Wr, Ur, partR);
    reader_pw<<<128, 256, 0, stream>>>(partR, br, h_r, c_r);

    for (int t = 0; t < Ll; ++t){
        const int p = t & (KK - 1);
        const int mode = (t == 0) ? 0 : ((p == 0) ? 1 : 2);
        const float* mi = (t <= KK) ? x : mem;   // memB = x until first materialize (t==KK) writes mem
        mega3<<<1024, 256, 0, stream>>>(mi, mem, h_r, scores, Mb, Sinv, part_me,
                                        Dv, Cv, hwring, mode, p);
        small_a<<<256, 256, 0, stream>>>(part_me, mrt, Mb, Sinv, hwring, (mode == 2) ? p : 0);
        int tn = (t + 1 < Ll) ? t + 1 : t;
        const float* hwprev = hwring + ((size_t)((t + KK - 1) & (KK - 1)) * Bb) * Dd;
        gemm_fast<<<(WSL + RSL) * 64, 256, 0, stream>>>(h_r, mrt, hwprev, Wf, partW,
                                                        x + (size_t)tn * Dd, Wr, Ur, partR);
        float* hwnew = hwring + ((size_t)(t & (KK - 1)) * Bb) * Dd;
        pw_both<<<256, 256, 0, stream>>>(partW, bf, hwnew, cw, out, t == Ll - 1 ? 1 : 0,
                                         partR, br, h_r, c_r);
    }
}